// Round 1
// 320.868 us; speedup vs baseline: 1.2892x; 1.2892x over previous
//
#include <hip/hip_runtime.h>
#include <hip/hip_bf16.h>

typedef __hip_bfloat16 bf16;
typedef __attribute__((ext_vector_type(8))) short short8;   // 8 bf16 (4 VGPRs)
typedef __attribute__((ext_vector_type(4))) float f32x4;    // 4 fp32 acc

#define PI2 6.283185307179586f
#define EPSV 1e-5f

__device__ __forceinline__ float bf(const bf16 v){ return __bfloat162float(v); }
__device__ __forceinline__ short f2bs(float f){
  bf16 h = __float2bfloat16(f);
  short s; __builtin_memcpy(&s, &h, 2); return s;
}
__device__ __forceinline__ float s2f(short s){
  bf16 h; __builtin_memcpy(&h, &s, 2); return __bfloat162float(h);
}

// ---------------- Prep A: weights->bf16 FRAGMENT layout, params, twiddles ----
// W1g/W2g are stored in MFMA b-fragment order so k_ffmain can stage them into
// LDS linearly and read frags at lds[fid*512 + lane*8] (conflict-free).
// frag id = (ch*4 + t)*2 + hb ; lane = quad*16 + l15 ; element e in [0,8)
//   W1: n = ch*64 + t*16 + l15 ; k = hb*32 + quad*8 + e ; val = l1w[k][n]
//   W2: n = t*16 + l15          ; k = ch*64 + hb*32 + quad*8 + e ; val = l2w[k][n]
__global__ __launch_bounds__(256) void k_prep_w(
    const float* __restrict__ b_l1w, const float* __restrict__ b_l1b,
    const float* __restrict__ b_l2w, const float* __restrict__ b_l2b,
    const float* __restrict__ b_g1w, const float* __restrict__ b_g1b,
    const float* __restrict__ b_g2w, const float* __restrict__ b_g2b,
    const float* __restrict__ b_g3w, const float* __restrict__ b_g3b,
    const float* __restrict__ f_l1w, const float* __restrict__ f_l1b,
    const float* __restrict__ f_l2w, const float* __restrict__ f_l2b,
    const float* __restrict__ f_g1w, const float* __restrict__ f_g1b,
    const float* __restrict__ f_g2w, const float* __restrict__ f_g2b,
    const float* __restrict__ f_g3w, const float* __restrict__ f_g3b,
    short* __restrict__ W1g, short* __restrict__ W2g,
    float2* __restrict__ TWY, float2* __restrict__ TWX,
    float* __restrict__ PB, float* __restrict__ ST){
  int i = blockIdx.x*256 + threadIdx.x;
  if(i < 32768){                         // W1g fragment layout
    int br = i >> 14, r = i & 16383;
    int fid = r >> 9, lane = (r >> 3) & 63, e = r & 7;
    int hb = fid & 1, t = (fid >> 1) & 3, ch = fid >> 3;
    int l15 = lane & 15, quad = lane >> 4;
    int n = ch*64 + t*16 + l15;
    int k = hb*32 + quad*8 + e;
    const float* src = br ? f_l1w : b_l1w;
    W1g[i] = f2bs(src[k*256 + n]);
    return;
  }
  i -= 32768;
  if(i < 32768){                         // W2g fragment layout
    int br = i >> 14, r = i & 16383;
    int fid = r >> 9, lane = (r >> 3) & 63, e = r & 7;
    int hb = fid & 1, t = (fid >> 1) & 3, ch = fid >> 3;
    int l15 = lane & 15, quad = lane >> 4;
    int n = t*16 + l15;
    int k = ch*64 + hb*32 + quad*8 + e;
    const float* src = br ? f_l2w : b_l2w;
    W2g[i] = f2bs(src[k*64 + n]);
    return;
  }
  i -= 32768;
  if(i < 2048){                          // TWY[ky][n]
    int ky = i >> 7, n = i & 127;
    float ang = PI2 * (float)((ky*n) & 127) / 128.0f;
    float s, c; sincosf(ang, &s, &c);
    TWY[i] = make_float2(c, s);
    return;
  }
  i -= 2048;
  if(i < 4096){                          // TWX[kp][m]
    int kp = i >> 7, m = i & 127;
    int kx = kp < 16 ? kp : 96 + kp;
    float ang = PI2 * (float)((kx*m) & 127) / 128.0f;
    float s, c; sincosf(ang, &s, &c);
    TWX[i] = make_float2(c, s);
    return;
  }
  i -= 4096;
  if(i < 384){ ST[i] = 0.f; return; }    // zero stats
  i -= 384;
  if(i < 2176){                          // param block
    int br = i >= 1088; int o = i - br*1088;
    float* pb = PB + br*2048;
    float v;
    if(o < 256)       v = (br ? f_l1b : b_l1b)[o];
    else if(o < 512)  v = (br ? f_g1w : b_g1w)[o-256];
    else if(o < 768)  v = (br ? f_g1b : b_g1b)[o-512];
    else if(o < 832)  v = (br ? f_l2b : b_l2b)[o-768];
    else if(o < 896)  v = (br ? f_g2w : b_g2w)[o-832];
    else if(o < 960)  v = (br ? f_g2b : b_g2b)[o-896];
    else if(o < 1024) v = (br ? f_g3w : b_g3w)[o-960];
    else              v = (br ? f_g3b : b_g3b)[o-1024];
    pb[o] = v;
  }
}

// ---------------- Prep B: transpose fw -> FWT[arr][kxw][ky][i][o] (fp32) -----
__global__ __launch_bounds__(256) void k_prep_fw(const float* __restrict__ fw1,
                                                 const float* __restrict__ fw2,
                                                 float2* __restrict__ FWT){
  __shared__ float Ls[16][512];
  int tid = threadIdx.x;
  int arr = blockIdx.x >> 8, rem = blockIdx.x & 255;
  int i = rem >> 2, o0 = (rem & 3) * 16;
  const float* src = (arr ? fw2 : fw1) + ((size_t)(i*64 + o0))*512;
  for(int idx = tid; idx < 8192; idx += 256)
    Ls[idx >> 9][idx & 511] = src[idx];
  __syncthreads();
  int kxw = tid >> 4, ky = tid & 15;
  float2* dst = FWT + ((size_t)((arr*16 + kxw)*16 + ky))*4096 + i*64 + o0;
  for(int ol = 0; ol < 16; ol++)
    dst[ol] = make_float2(Ls[ol][tid*2], Ls[ol][tid*2 + 1]);
}

// ---------------- Stage 1: x4 = x - backcast; DFT over y (16 modes) ----------
__global__ __launch_bounds__(256) void k_ydft(const float* __restrict__ x,
                                              const float* __restrict__ z,
                                              const float2* __restrict__ TWY,
                                              float2* __restrict__ Y){
  __shared__ float Xs[128][64];
  __shared__ float twc[16][128];
  __shared__ float tws[16][128];
  int b = blockIdx.x >> 7, m = blockIdx.x & 127;
  int tid = threadIdx.x;
  const float4* xp = (const float4*)(x + ((size_t)(b*128 + m)*128)*64);
  const float4* zp = (const float4*)(z + ((size_t)((b*2 + 0)*128 + m)*128)*64);
  float4* xs4 = (float4*)&Xs[0][0];
  for(int idx = tid; idx < 2048; idx += 256){
    float4 a = xp[idx], c = zp[idx];
    xs4[idx] = make_float4(a.x-c.x, a.y-c.y, a.z-c.z, a.w-c.w);
  }
  for(int idx = tid; idx < 2048; idx += 256){
    float2 t = TWY[idx];
    twc[idx>>7][idx&127] = t.x; tws[idx>>7][idx&127] = t.y;
  }
  __syncthreads();
  int i = tid & 63, kq = tid >> 6;
  for(int j = 0; j < 4; j++){
    int ky = kq*4 + j;
    float re = 0.f, im = 0.f;
    #pragma unroll 4
    for(int n = 0; n < 128; n++){
      float v = Xs[n][i];
      re += v * twc[ky][n];
      im -= v * tws[ky][n];
    }
    Y[((b*128 + m)*16 + ky)*64 + i] = make_float2(re, im);
  }
}

// ------- Stage 2: DFT over x (32 modes), grid 256 (b,ky,kp-half,i-half) ------
__global__ __launch_bounds__(128) void k_xdft(const float2* __restrict__ Y,
                                              const float2* __restrict__ TWX,
                                              float2* __restrict__ X2){
  __shared__ float twc[16][128];
  __shared__ float tws[16][128];
  int bi = blockIdx.x;
  int b = bi >> 6, ky = (bi >> 2) & 15, half = (bi >> 1) & 1, ih = bi & 1;
  int tid = threadIdx.x;
  for(int idx = tid; idx < 2048; idx += 128){
    int kpl = idx >> 7, m = idx & 127;
    float2 t = TWX[(half*16 + kpl)*128 + m];
    twc[kpl][m] = t.x; tws[kpl][m] = t.y;
  }
  __syncthreads();
  int i = ih*32 + (tid & 31), grp = tid >> 5;
  float re[4], im[4];
  #pragma unroll
  for(int j = 0; j < 4; j++){ re[j] = 0.f; im[j] = 0.f; }
  for(int m = 0; m < 128; m++){
    float2 y = Y[((b*128 + m)*16 + ky)*64 + i];
    #pragma unroll
    for(int j = 0; j < 4; j++){
      int kpl = grp*4 + j;
      float c = twc[kpl][m], s = tws[kpl][m];
      re[j] += y.x*c + y.y*s;
      im[j] += y.y*c - y.x*s;
    }
  }
  const float sc = 1.0f/128.0f;   // forward ortho norm (both axes)
  #pragma unroll
  for(int j = 0; j < 4; j++){
    int kp = half*16 + grp*4 + j;
    X2[((b*32 + kp)*16 + ky)*64 + i] = make_float2(re[j]*sc, im[j]*sc);
  }
}

// ------- Stage 3: per-mode 64x64 complex mix, coalesced FWT, 4 waves/block ---
__global__ __launch_bounds__(256) void k_mix(float2* __restrict__ X2,
                                             const float2* __restrict__ FWT){
  __shared__ float2 Xs[4][4][64];   // [pair_local][batch][i]
  int tid = threadIdx.x;
  for(int idx = tid; idx < 1024; idx += 256){
    int pl = idx >> 8, b = (idx >> 6) & 3, i = idx & 63;
    int p = blockIdx.x*4 + pl; int kp = p >> 4, ky = p & 15;
    Xs[pl][b][i] = X2[((b*32 + kp)*16 + ky)*64 + i];
  }
  __syncthreads();
  int w = tid >> 6, o = tid & 63;
  int p = blockIdx.x*4 + w; int kp = p >> 4, ky = p & 15;
  int arr = kp < 16 ? 0 : 1, kxw = kp < 16 ? kp : kp - 16;
  const float2* wp = FWT + ((size_t)((arr*16 + kxw)*16 + ky))*4096;
  float rr[4] = {0,0,0,0}, ii[4] = {0,0,0,0};
  for(int i = 0; i < 64; i++){
    float2 wv = wp[i*64 + o];
    #pragma unroll
    for(int b = 0; b < 4; b++){
      float xr = Xs[w][b][i].x, xi = Xs[w][b][i].y;
      rr[b] += xr*wv.x - xi*wv.y;
      ii[b] += xr*wv.y + xi*wv.x;
    }
  }
  for(int b = 0; b < 4; b++)
    X2[((b*32 + kp)*16 + ky)*64 + o] = make_float2(rr[b], ii[b]);
}

// ------- Stage 4: inverse DFT over kx, grid 256 (b,ky,m-half,o-half) ---------
__global__ __launch_bounds__(128) void k_inv1(const float2* __restrict__ OF,
                                              const float2* __restrict__ TWX,
                                              float2* __restrict__ T){
  __shared__ float2 F[32][32];
  __shared__ float twc[32][64];
  __shared__ float tws[32][64];
  int bi = blockIdx.x;
  int b = bi >> 6, ky = (bi >> 2) & 15, mh = (bi >> 1) & 1, oh = bi & 1;
  int tid = threadIdx.x;
  for(int idx = tid; idx < 1024; idx += 128){
    int kp = idx >> 5, ol = idx & 31;
    F[kp][ol] = OF[((b*32 + kp)*16 + ky)*64 + oh*32 + ol];
  }
  for(int idx = tid; idx < 2048; idx += 128){
    int kp = idx >> 6, ml = idx & 63;
    float2 t = TWX[kp*128 + mh*64 + ml];
    twc[kp][ml] = t.x; tws[kp][ml] = t.y;
  }
  __syncthreads();
  int ol = tid & 31, mg = tid >> 5;
  int o = oh*32 + ol;
  for(int ml = mg*16; ml < mg*16 + 16; ml++){
    int m = mh*64 + ml;
    float re = 0.f, im = 0.f;
    #pragma unroll 4
    for(int kp = 0; kp < 32; kp++){
      float c = twc[kp][ml], s = tws[kp][ml];
      float fr = F[kp][ol].x, fi = F[kp][ol].y;
      re += fr*c - fi*s;
      im += fr*s + fi*c;
    }
    T[((b*128 + m)*16 + ky)*64 + o] = make_float2(re, im);
  }
}

// ---------------- Stage 5: hermitian inverse over ky (C2R), store bf16 -------
// Also zeroes the Cg/SX accumulators (aliased into the now-dead FWT region).
__global__ __launch_bounds__(256) void k_inv2(const float2* __restrict__ T,
                                              const float2* __restrict__ TWY,
                                              bf16* __restrict__ XO,
                                              float* __restrict__ CZ){
  __shared__ float2 Tl[16][64];
  __shared__ float twc[16][128];
  __shared__ float tws[16][128];
  int b = blockIdx.x >> 7, m = blockIdx.x & 127;
  int tid = threadIdx.x;
  int flat = blockIdx.x*256 + tid;
  if(flat < 16640) CZ[flat] = 0.f;      // zero Cg (16384) + SX (256)
  for(int idx = tid; idx < 1024; idx += 256){
    int ky = idx >> 6, o = idx & 63;
    Tl[ky][o] = T[((b*128 + m)*16 + ky)*64 + o];
  }
  for(int idx = tid; idx < 2048; idx += 256){
    float2 t = TWY[idx];
    twc[idx>>7][idx&127] = t.x; tws[idx>>7][idx&127] = t.y;
  }
  __syncthreads();
  int o = tid & 63, ng = tid >> 6;
  const float sc = 1.0f/128.0f;   // inverse ortho norm (both axes)
  for(int n = ng*32; n < ng*32 + 32; n++){
    float v = Tl[0][o].x;         // C2R ignores Im of DC bin
    #pragma unroll
    for(int ky = 1; ky < 16; ky++)
      v += 2.0f*(Tl[ky][o].x*twc[ky][n] - Tl[ky][o].y*tws[ky][n]);
    XO[((b*128 + m)*128 + n)*64 + o] = __float2bfloat16(v*sc);
  }
}

// ------- Cov: S = X^T X (64x64) and sx = colsum(X) per b, via MFMA -----------
// grid 256: b = bi>>6, 256-position chunk = bi&63. Replaces the GEMM1 re-run.
__global__ __launch_bounds__(256) void k_cov(const bf16* __restrict__ XO,
                                             float* __restrict__ Cg,
                                             float* __restrict__ SX){
  __shared__ short XT[64][264];    // [ch][pos], padded row (528B, 16B-aligned)
  __shared__ float sxl[64];
  int tid = threadIdx.x;
  int b = blockIdx.x >> 6, ck = blockIdx.x & 63;
  size_t pbase = (size_t)b*16384 + (size_t)ck*256;
  if(tid < 64) sxl[tid] = 0.f;
  __syncthreads();
  float sxp[8];
  #pragma unroll
  for(int e = 0; e < 8; e++) sxp[e] = 0.f;
  int c0 = (tid & 7)*8;
  const short* xg = (const short*)XO + pbase*64;
  for(int it = 0; it < 8; it++){
    int p = it*32 + (tid >> 3);
    short8 v = *(const short8*)(xg + (size_t)p*64 + c0);
    #pragma unroll
    for(int e = 0; e < 8; e++){
      XT[c0+e][p] = v[e];
      sxp[e] += s2f(v[e]);
    }
  }
  #pragma unroll
  for(int e = 0; e < 8; e++) atomicAdd(&sxl[c0+e], sxp[e]);
  __syncthreads();
  int lane = tid & 63, w = tid >> 6, l15 = lane & 15, quad = lane >> 4;
  f32x4 acc[4];
  #pragma unroll
  for(int tj = 0; tj < 4; tj++) acc[tj] = (f32x4){0.f,0.f,0.f,0.f};
  for(int kk = 0; kk < 8; kk++){
    short8 a = *(const short8*)&XT[w*16 + l15][kk*32 + quad*8];
    #pragma unroll
    for(int tj = 0; tj < 4; tj++){
      short8 bfr = *(const short8*)&XT[tj*16 + l15][kk*32 + quad*8];
      acc[tj] = __builtin_amdgcn_mfma_f32_16x16x32_bf16(a, bfr, acc[tj], 0, 0, 0);
    }
  }
  float* Cb = Cg + b*4096;
  #pragma unroll
  for(int tj = 0; tj < 4; tj++)
    #pragma unroll
    for(int r = 0; r < 4; r++)
      atomicAdd(&Cb[(w*16 + quad*4 + r)*64 + tj*16 + l15], acc[tj][r]);
  if(tid < 64) atomicAdd(&SX[b*64 + tid], sxl[tid]);
}

// ------- Stat: GN1 group sums from quadratic form; writes S1 directly --------
// Sum h   = sx.w_n + P*b_n ; Sum h^2 = w^T S w + 2 b_n (sx.w_n) + P*b_n^2
// grid 128: br = bi>>6, b = (bi>>4)&3, group g = bi&15.
__global__ __launch_bounds__(256) void k_stat(const float* __restrict__ Cg,
                                              const float* __restrict__ SX,
                                              const short* __restrict__ W1g,
                                              const float* __restrict__ PB,
                                              float* __restrict__ ST){
  __shared__ float Cl[64][65];
  __shared__ float Wl[16][64];
  __shared__ float sxl[64];
  __shared__ float g2[2];
  int tid = threadIdx.x;
  int br = blockIdx.x >> 6, b = (blockIdx.x >> 4) & 3, g = blockIdx.x & 15;
  const float* Cb = Cg + b*4096;
  for(int u = tid; u < 4096; u += 256) Cl[u >> 6][u & 63] = Cb[u];
  const short* W1 = W1g + br*16384;
  for(int u = tid; u < 1024; u += 256){
    int nl = u >> 6, k = u & 63;
    int n = g*16 + nl;
    int fid = ((n >> 6)*4 + ((n >> 4) & 3))*2 + (k >> 5);
    int lane = ((k >> 3) & 3)*16 + (n & 15);
    Wl[nl][k] = s2f(W1[fid*512 + lane*8 + (k & 7)]);
  }
  if(tid < 64) sxl[tid] = SX[b*64 + tid];
  if(tid < 2) g2[tid] = 0.f;
  __syncthreads();
  int nl = tid >> 4, ic = tid & 15;
  float qa = 0.f, sa = 0.f;
  for(int io = 0; io < 4; io++){
    int i = ic*4 + io;
    float wi = Wl[nl][i];
    float dot = 0.f;
    #pragma unroll 8
    for(int j = 0; j < 64; j++) dot += Cl[i][j]*Wl[nl][j];
    qa += wi*dot;
    sa += wi*sxl[i];
  }
  for(int off = 8; off; off >>= 1){
    qa += __shfl_xor(qa, off);
    sa += __shfl_xor(sa, off);
  }
  if(ic == 0){
    float bn = PB[br*2048 + g*16 + nl];
    float hs = sa + 16384.f*bn;
    float hq = qa + 2.f*bn*sa + 16384.f*bn*bn;
    atomicAdd(&g2[0], hs); atomicAdd(&g2[1], hq);
  }
  __syncthreads();
  if(tid == 0){
    float* S1 = ST + br*192;
    S1[(b*16 + g)*2]     = g2[0];
    S1[(b*16 + g)*2 + 1] = g2[1];
  }
}

// ------- FF main: GEMM1+GN1+relu+GEMM2 -> h2 fp32 + GN2 stats ----------------
// grid 512 = br(2) x 256-row blocks; weights staged once to LDS in frag order;
// NO barriers in the K loop (Hn rows are wave-private; DS pipe is in-order).
__global__ __launch_bounds__(256, 2) void k_ffmain(const bf16* __restrict__ XO,
                                                   const short* __restrict__ W1g,
                                                   const short* __restrict__ W2g,
                                                   const float* __restrict__ PB,
                                                   float* __restrict__ ST,
                                                   float* __restrict__ out){
  __shared__ short Ws1[16384];     // 32KB frag-order W1
  __shared__ short Ws2[16384];     // 32KB frag-order W2
  __shared__ short Hn[64][72];     // per-wave-private row slices
  __shared__ float mu1[16], rs1[16];
  __shared__ float gs[4], gq[4];
  int tid = threadIdx.x;
  int br = blockIdx.x >> 8, rb = blockIdx.x & 255;
  int r0 = rb << 8, b = rb >> 6;
  const float* pb = PB + br*2048;
  {
    const uint4* g1 = (const uint4*)(W1g + br*16384);
    const uint4* g2w = (const uint4*)(W2g + br*16384);
    uint4* s1 = (uint4*)Ws1; uint4* s2 = (uint4*)Ws2;
    #pragma unroll
    for(int u = 0; u < 8; u++){
      s1[u*256 + tid] = g1[u*256 + tid];
      s2[u*256 + tid] = g2w[u*256 + tid];
    }
  }
  if(tid < 16){
    const float cnt = 262144.f;  // 128*128*16
    const float* S1 = ST + br*192;
    float s = S1[(b*16 + tid)*2], q = S1[(b*16 + tid)*2 + 1];
    float mean = s/cnt, var = q/cnt - mean*mean;
    mu1[tid] = mean; rs1[tid] = rsqrtf(fmaxf(var, 0.f) + EPSV);
  }
  if(tid < 4){ gs[tid] = 0.f; gq[tid] = 0.f; }
  __syncthreads();
  int lane = tid & 63, w = tid >> 6, l15 = lane & 15, quad = lane >> 4;
  int myrow = w*16 + l15;
  float sacc[4] = {0.f,0.f,0.f,0.f}, qacc[4] = {0.f,0.f,0.f,0.f};
  for(int c = 0; c < 4; c++){
    const short* xop = (const short*)XO + ((size_t)(r0 + c*64 + myrow))*64;
    short8 a0 = *(const short8*)(xop + quad*8);
    short8 a1 = *(const short8*)(xop + 32 + quad*8);
    f32x4 acc2[4];
    #pragma unroll
    for(int t = 0; t < 4; t++) acc2[t] = (f32x4){0.f,0.f,0.f,0.f};
    for(int ch = 0; ch < 4; ch++){
      #pragma unroll
      for(int t = 0; t < 4; t++){
        int fid = (ch*4 + t)*2;
        short8 b0 = *(const short8*)(Ws1 + fid*512 + lane*8);
        short8 b1 = *(const short8*)(Ws1 + fid*512 + 512 + lane*8);
        f32x4 acc = {0.f,0.f,0.f,0.f};
        acc = __builtin_amdgcn_mfma_f32_16x16x32_bf16(a0, b0, acc, 0, 0, 0);
        acc = __builtin_amdgcn_mfma_f32_16x16x32_bf16(a1, b1, acc, 0, 0, 0);
        int n = ch*64 + t*16 + l15, gi = n >> 4;
        float w1v = pb[256 + n];
        float gwv = w1v * rs1[gi];
        float gbv = (pb[n] - mu1[gi])*rs1[gi]*w1v + pb[512 + n];
        #pragma unroll
        for(int r = 0; r < 4; r++){
          float hv = acc[r]*gwv + gbv;
          hv = hv > 0.f ? hv : 0.f;
          Hn[w*16 + quad*4 + r][t*16 + l15] = f2bs(hv);
        }
      }
      short8 ha0 = *(short8*)&Hn[myrow][quad*8];
      short8 ha1 = *(short8*)&Hn[myrow][32 + quad*8];
      #pragma unroll
      for(int t = 0; t < 4; t++){
        int fid = (ch*4 + t)*2;
        short8 b0 = *(const short8*)(Ws2 + fid*512 + lane*8);
        short8 b1 = *(const short8*)(Ws2 + fid*512 + 512 + lane*8);
        acc2[t] = __builtin_amdgcn_mfma_f32_16x16x32_bf16(ha0, b0, acc2[t], 0, 0, 0);
        acc2[t] = __builtin_amdgcn_mfma_f32_16x16x32_bf16(ha1, b1, acc2[t], 0, 0, 0);
      }
    }
    float* obase = out + ((size_t)(b*2 + br)*16384 + (r0 & 16383) + c*64)*64;
    #pragma unroll
    for(int t = 0; t < 4; t++){
      int col = t*16 + l15;
      float bias2 = pb[768 + col];
      #pragma unroll
      for(int r = 0; r < 4; r++){
        float h2 = acc2[t][r] + bias2;
        obase[(size_t)(w*16 + quad*4 + r)*64 + col] = h2;
        sacc[t] += h2; qacc[t] += h2*h2;
      }
    }
  }
  #pragma unroll
  for(int t = 0; t < 4; t++){
    float s = sacc[t], q = qacc[t];
    for(int off = 32; off; off >>= 1){
      s += __shfl_xor(s, off); q += __shfl_xor(q, off);
    }
    if(lane == 0){ atomicAdd(&gs[t], s); atomicAdd(&gq[t], q); }
  }
  __syncthreads();
  if(tid < 4){
    float* S2 = ST + br*192 + 128;
    atomicAdd(&S2[(b*4 + tid)*2],     gs[tid]);
    atomicAdd(&S2[(b*4 + tid)*2 + 1], gq[tid]);
  }
}

// ------- FF stage C: t = res + GN2(h2) in place + GN3 stats; both branches ---
__global__ __launch_bounds__(256) void k_ff3(const float* __restrict__ z,
                                             const float* __restrict__ PB,
                                             float* __restrict__ ST,
                                             float* __restrict__ out){
  __shared__ float mu2[4], rs2[4];
  __shared__ float gs[4], gq[4];
  int br = blockIdx.x >> 9, rest = blockIdx.x & 511;
  int b = rest >> 7, m = rest & 127;
  int tid = threadIdx.x;
  const float* pb = PB + br*2048;
  float* S2 = ST + br*192 + 128;
  if(tid < 4){
    const float cnt = 262144.f;
    float s = S2[(b*4 + tid)*2], q = S2[(b*4 + tid)*2 + 1];
    float mean = s/cnt, var = q/cnt - mean*mean;
    mu2[tid] = mean; rs2[tid] = rsqrtf(var + EPSV);
    gs[tid] = 0.f; gq[tid] = 0.f;
  }
  __syncthreads();
  int o = tid & 63, ng = tid >> 6;
  int g = o >> 4;
  float w2v = pb[832 + o];
  float gw = w2v*rs2[g];
  float gb = pb[896 + o] - mu2[g]*rs2[g]*w2v;
  float s = 0.f, q = 0.f;
  float* op = out + ((size_t)((b*2 + br)*128 + m)*128)*64 + o;
  const float* zp = z + ((size_t)((b*2 + br)*128 + m)*128)*64 + o;
  for(int n = ng*32; n < ng*32 + 32; n++){
    float h2 = op[n*64];
    float t = zp[n*64] + h2*gw + gb;
    op[n*64] = t;
    s += t; q += t*t;
  }
  atomicAdd(&gs[g], s);
  atomicAdd(&gq[g], q);
  __syncthreads();
  float* S3 = ST + br*192 + 160;
  if(tid < 4){
    atomicAdd(&S3[(b*4 + tid)*2 + 0], gs[tid]);
    atomicAdd(&S3[(b*4 + tid)*2 + 1], gq[tid]);
  }
}

// ---------------- FF stage D: out = GN3(t) in place; both branches -----------
__global__ __launch_bounds__(256) void k_ff4(const float* __restrict__ PB,
                                             const float* __restrict__ ST,
                                             float* __restrict__ out){
  __shared__ float mu3[4], rs3[4];
  int br = blockIdx.x >> 9, rest = blockIdx.x & 511;
  int b = rest >> 7, m = rest & 127;
  int tid = threadIdx.x;
  const float* pb = PB + br*2048;
  const float* S3 = ST + br*192 + 160;
  if(tid < 4){
    const float cnt = 262144.f;
    float s = S3[(b*4 + tid)*2], q = S3[(b*4 + tid)*2 + 1];
    float mean = s/cnt, var = q/cnt - mean*mean;
    mu3[tid] = mean; rs3[tid] = rsqrtf(var + EPSV);
  }
  __syncthreads();
  int o = tid & 63, ng = tid >> 6;
  int g = o >> 4;
  float w3v = pb[960 + o];
  float gw = w3v*rs3[g];
  float gb = pb[1024 + o] - mu3[g]*rs3[g]*w3v;
  float* op = out + ((size_t)((b*2 + br)*128 + m)*128)*64 + o;
  for(int n = ng*32; n < ng*32 + 32; n++){
    float t = op[n*64];
    op[n*64] = t*gw + gb;
  }
}

extern "C" void kernel_launch(void* const* d_in, const int* in_sizes, int n_in,
                              void* d_out, int out_size, void* d_ws, size_t ws_size,
                              hipStream_t stream){
  const float* z   = (const float*)d_in[0];
  const float* x   = (const float*)d_in[1];
  const float* fw1 = (const float*)d_in[2];
  const float* fw2 = (const float*)d_in[3];
  char* ws = (char*)d_ws;
  // workspace layout (byte offsets), total ~30.6 MB (unchanged)
  float2* Y   = (float2*)(ws + 0);           // 4,194,304 B
  float2* X2  = (float2*)(ws + 4194304);     // 1,048,576 B
  float2* T   = Y;                           // alias: Y dead after k_xdft
  bf16*   XO  = (bf16*)(ws + 5242880);       // 8,388,608 B
  float*  ST  = (float*)(ws + 13631488);     // 1,536 B
  short*  W1g = (short*)(ws + 13633536);     // 65,536 B
  short*  W2g = (short*)(ws + 13699072);     // 65,536 B
  float2* TWY = (float2*)(ws + 13764608);    // 16,384 B
  float2* TWX = (float2*)(ws + 13780992);    // 32,768 B
  float*  PB  = (float*)(ws + 13813760);     // 16,384 B
  float2* FWT = (float2*)(ws + 13830144);    // 16,777,216 B -> ends 30,607,360
  // Cg/SX alias the FWT region (FWT is dead after k_mix; zeroed in k_inv2)
  float*  Cg  = (float*)(ws + 13830144);     // 65,536 B (4 x 64 x 64)
  float*  SX  = Cg + 16384;                  // 1,024 B  (4 x 64)

  const float* p[20];
  for(int i = 0; i < 20; i++) p[i] = (const float*)d_in[4 + i];

  k_prep_w<<<290, 256, 0, stream>>>(p[0],p[1],p[2],p[3],p[4],p[5],p[6],p[7],p[8],p[9],
                                    p[10],p[11],p[12],p[13],p[14],p[15],p[16],p[17],p[18],p[19],
                                    W1g, W2g, TWY, TWX, PB, ST);
  k_prep_fw<<<512, 256, 0, stream>>>(fw1, fw2, FWT);
  k_ydft<<<512, 256, 0, stream>>>(x, z, TWY, Y);
  k_xdft<<<256, 128, 0, stream>>>(Y, TWX, X2);
  k_mix<<<128, 256, 0, stream>>>(X2, FWT);
  k_inv1<<<256, 128, 0, stream>>>(X2, TWX, T);
  k_inv2<<<512, 256, 0, stream>>>(T, TWY, XO, Cg);
  k_cov<<<256, 256, 0, stream>>>(XO, Cg, SX);
  k_stat<<<128, 256, 0, stream>>>(Cg, SX, W1g, PB, ST);
  k_ffmain<<<512, 256, 0, stream>>>(XO, W1g, W2g, PB, ST, (float*)d_out);
  k_ff3<<<1024, 256, 0, stream>>>(z, PB, ST, (float*)d_out);
  k_ff4<<<1024, 256, 0, stream>>>(PB, ST, (float*)d_out);
}

// Round 2
// 299.454 us; speedup vs baseline: 1.3814x; 1.0715x over previous
//
#include <hip/hip_runtime.h>
#include <hip/hip_bf16.h>

typedef __hip_bfloat16 bf16;
typedef __attribute__((ext_vector_type(8))) short short8;   // 8 bf16 (4 VGPRs)
typedef __attribute__((ext_vector_type(4))) float f32x4;    // 4 fp32 acc

#define PI2 6.283185307179586f
#define EPSV 1e-5f

__device__ __forceinline__ short f2bs(float f){
  bf16 h = __float2bfloat16(f);
  short s; __builtin_memcpy(&s, &h, 2); return s;
}
__device__ __forceinline__ float s2f(short s){
  bf16 h; __builtin_memcpy(&h, &s, 2); return __bfloat162float(h);
}

// ---------------- Prep (merged): fw transpose + weights/params/twiddles ------
// blocks [0,512): FWT transpose ; blocks [512,802): weights/params/twiddles
__global__ __launch_bounds__(256) void k_prep(
    const float* __restrict__ fw1, const float* __restrict__ fw2,
    float2* __restrict__ FWT,
    const float* __restrict__ b_l1w, const float* __restrict__ b_l1b,
    const float* __restrict__ b_l2w, const float* __restrict__ b_l2b,
    const float* __restrict__ b_g1w, const float* __restrict__ b_g1b,
    const float* __restrict__ b_g2w, const float* __restrict__ b_g2b,
    const float* __restrict__ b_g3w, const float* __restrict__ b_g3b,
    const float* __restrict__ f_l1w, const float* __restrict__ f_l1b,
    const float* __restrict__ f_l2w, const float* __restrict__ f_l2b,
    const float* __restrict__ f_g1w, const float* __restrict__ f_g1b,
    const float* __restrict__ f_g2w, const float* __restrict__ f_g2b,
    const float* __restrict__ f_g3w, const float* __restrict__ f_g3b,
    short* __restrict__ W1g, short* __restrict__ W2g,
    float2* __restrict__ TWY, float2* __restrict__ TWX,
    float* __restrict__ PB, float* __restrict__ ST){
  __shared__ float Ls[16][512];
  int tid = threadIdx.x;
  if(blockIdx.x < 512){
    int arr = blockIdx.x >> 8, rem = blockIdx.x & 255;
    int i = rem >> 2, o0 = (rem & 3) * 16;
    const float* src = (arr ? fw2 : fw1) + ((size_t)(i*64 + o0))*512;
    for(int idx = tid; idx < 8192; idx += 256)
      Ls[idx >> 9][idx & 511] = src[idx];
    __syncthreads();
    int kxw = tid >> 4, ky = tid & 15;
    float2* dst = FWT + ((size_t)((arr*16 + kxw)*16 + ky))*4096 + i*64 + o0;
    for(int ol = 0; ol < 16; ol++)
      dst[ol] = make_float2(Ls[ol][tid*2], Ls[ol][tid*2 + 1]);
    return;
  }
  int i = (blockIdx.x - 512)*256 + tid;
  if(i < 32768){                         // W1g fragment layout
    int br = i >> 14, r = i & 16383;
    int fid = r >> 9, lane = (r >> 3) & 63, e = r & 7;
    int hb = fid & 1, t = (fid >> 1) & 3, ch = fid >> 3;
    int l15 = lane & 15, quad = lane >> 4;
    int n = ch*64 + t*16 + l15;
    int k = hb*32 + quad*8 + e;
    const float* src = br ? f_l1w : b_l1w;
    W1g[i] = f2bs(src[k*256 + n]);
    return;
  }
  i -= 32768;
  if(i < 32768){                         // W2g fragment layout
    int br = i >> 14, r = i & 16383;
    int fid = r >> 9, lane = (r >> 3) & 63, e = r & 7;
    int hb = fid & 1, t = (fid >> 1) & 3, ch = fid >> 3;
    int l15 = lane & 15, quad = lane >> 4;
    int n = t*16 + l15;
    int k = ch*64 + hb*32 + quad*8 + e;
    const float* src = br ? f_l2w : b_l2w;
    W2g[i] = f2bs(src[k*64 + n]);
    return;
  }
  i -= 32768;
  if(i < 2048){                          // TWY[ky][n]
    int ky = i >> 7, n = i & 127;
    float ang = PI2 * (float)((ky*n) & 127) / 128.0f;
    float s, c; sincosf(ang, &s, &c);
    TWY[i] = make_float2(c, s);
    return;
  }
  i -= 2048;
  if(i < 4096){                          // TWX[kp][m]
    int kp = i >> 7, m = i & 127;
    int kx = kp < 16 ? kp : 96 + kp;
    float ang = PI2 * (float)((kx*m) & 127) / 128.0f;
    float s, c; sincosf(ang, &s, &c);
    TWX[i] = make_float2(c, s);
    return;
  }
  i -= 4096;
  if(i < 384){ ST[i] = 0.f; return; }    // zero stats
  i -= 384;
  if(i < 2176){                          // param block
    int br = i >= 1088; int o = i - br*1088;
    float* pb = PB + br*2048;
    float v;
    if(o < 256)       v = (br ? f_l1b : b_l1b)[o];
    else if(o < 512)  v = (br ? f_g1w : b_g1w)[o-256];
    else if(o < 768)  v = (br ? f_g1b : b_g1b)[o-512];
    else if(o < 832)  v = (br ? f_l2b : b_l2b)[o-768];
    else if(o < 896)  v = (br ? f_g2w : b_g2w)[o-832];
    else if(o < 960)  v = (br ? f_g2b : b_g2b)[o-896];
    else if(o < 1024) v = (br ? f_g3w : b_g3w)[o-960];
    else              v = (br ? f_g3b : b_g3b)[o-1024];
    pb[o] = v;
  }
}

// ---------------- Stage 1: x4 = x - backcast; DFT over y (16 modes) ----------
// n-outer / ky-inner: Xs value loaded once per n; twiddles read as b64 bcast.
__global__ __launch_bounds__(256) void k_ydft(const float* __restrict__ x,
                                              const float* __restrict__ z,
                                              const float2* __restrict__ TWY,
                                              float2* __restrict__ Y){
  __shared__ float Xs[128][64];
  __shared__ float2 twl[16][128];
  int b = blockIdx.x >> 7, m = blockIdx.x & 127;
  int tid = threadIdx.x;
  const float4* xp = (const float4*)(x + ((size_t)(b*128 + m)*128)*64);
  const float4* zp = (const float4*)(z + ((size_t)((b*2 + 0)*128 + m)*128)*64);
  float4* xs4 = (float4*)&Xs[0][0];
  for(int idx = tid; idx < 2048; idx += 256){
    float4 a = xp[idx], c = zp[idx];
    xs4[idx] = make_float4(a.x-c.x, a.y-c.y, a.z-c.z, a.w-c.w);
  }
  for(int idx = tid; idx < 2048; idx += 256)
    twl[idx >> 7][idx & 127] = TWY[idx];
  __syncthreads();
  int i = tid & 63, kq = tid >> 6;
  float re[4] = {0,0,0,0}, im[4] = {0,0,0,0};
  for(int n = 0; n < 128; n++){
    float v = Xs[n][i];
    #pragma unroll
    for(int j = 0; j < 4; j++){
      float2 t = twl[kq*4 + j][n];
      re[j] += v*t.x;
      im[j] -= v*t.y;
    }
  }
  #pragma unroll
  for(int j = 0; j < 4; j++)
    Y[((b*128 + m)*16 + kq*4 + j)*64 + i] = make_float2(re[j], im[j]);
}

// ------- Stage 2: DFT over x (32 modes), grid 256 (b,ky,kp-half,i-half) ------
__global__ __launch_bounds__(128) void k_xdft(const float2* __restrict__ Y,
                                              const float2* __restrict__ TWX,
                                              float2* __restrict__ X2){
  __shared__ float2 twl[16][128];
  int bi = blockIdx.x;
  int b = bi >> 6, ky = (bi >> 2) & 15, half = (bi >> 1) & 1, ih = bi & 1;
  int tid = threadIdx.x;
  for(int idx = tid; idx < 2048; idx += 128)
    twl[idx >> 7][idx & 127] = TWX[(half << 11) + idx];
  __syncthreads();
  int i = ih*32 + (tid & 31), grp = tid >> 5;
  float re[4], im[4];
  #pragma unroll
  for(int j = 0; j < 4; j++){ re[j] = 0.f; im[j] = 0.f; }
  #pragma unroll 4
  for(int m = 0; m < 128; m++){
    float2 y = Y[((b*128 + m)*16 + ky)*64 + i];
    #pragma unroll
    for(int j = 0; j < 4; j++){
      float2 t = twl[grp*4 + j][m];
      re[j] += y.x*t.x + y.y*t.y;
      im[j] += y.y*t.x - y.x*t.y;
    }
  }
  const float sc = 1.0f/128.0f;   // forward ortho norm (both axes)
  #pragma unroll
  for(int j = 0; j < 4; j++){
    int kp = half*16 + grp*4 + j;
    X2[((b*32 + kp)*16 + ky)*64 + i] = make_float2(re[j]*sc, im[j]*sc);
  }
}

// ------- Stage 3: per-mode 64x64 complex mix, coalesced FWT, 4 waves/block ---
__global__ __launch_bounds__(256) void k_mix(float2* __restrict__ X2,
                                             const float2* __restrict__ FWT){
  __shared__ float2 Xs[4][4][64];   // [pair_local][batch][i]
  int tid = threadIdx.x;
  for(int idx = tid; idx < 1024; idx += 256){
    int pl = idx >> 8, b = (idx >> 6) & 3, i = idx & 63;
    int p = blockIdx.x*4 + pl; int kp = p >> 4, ky = p & 15;
    Xs[pl][b][i] = X2[((b*32 + kp)*16 + ky)*64 + i];
  }
  __syncthreads();
  int w = tid >> 6, o = tid & 63;
  int p = blockIdx.x*4 + w; int kp = p >> 4, ky = p & 15;
  int arr = kp < 16 ? 0 : 1, kxw = kp < 16 ? kp : kp - 16;
  const float2* wp = FWT + ((size_t)((arr*16 + kxw)*16 + ky))*4096;
  float rr[4] = {0,0,0,0}, ii[4] = {0,0,0,0};
  for(int i = 0; i < 64; i++){
    float2 wv = wp[i*64 + o];
    #pragma unroll
    for(int b = 0; b < 4; b++){
      float xr = Xs[w][b][i].x, xi = Xs[w][b][i].y;
      rr[b] += xr*wv.x - xi*wv.y;
      ii[b] += xr*wv.y + xi*wv.x;
    }
  }
  for(int b = 0; b < 4; b++)
    X2[((b*32 + kp)*16 + ky)*64 + o] = make_float2(rr[b], ii[b]);
}

// ------- Stage 4: inverse DFT over kx; kp-outer, 16 ml accumulators ----------
__global__ __launch_bounds__(128) void k_inv1(const float2* __restrict__ OF,
                                              const float2* __restrict__ TWX,
                                              float2* __restrict__ T){
  __shared__ float2 F[32][32];
  __shared__ float2 twl[32][64];
  int bi = blockIdx.x;
  int b = bi >> 6, ky = (bi >> 2) & 15, mh = (bi >> 1) & 1, oh = bi & 1;
  int tid = threadIdx.x;
  for(int idx = tid; idx < 1024; idx += 128){
    int kp = idx >> 5, ol = idx & 31;
    F[kp][ol] = OF[((b*32 + kp)*16 + ky)*64 + oh*32 + ol];
  }
  for(int idx = tid; idx < 2048; idx += 128){
    int kp = idx >> 6, ml = idx & 63;
    twl[kp][ml] = TWX[kp*128 + mh*64 + ml];
  }
  __syncthreads();
  int ol = tid & 31, mg = tid >> 5;
  float re[16], im[16];
  #pragma unroll
  for(int u = 0; u < 16; u++){ re[u] = 0.f; im[u] = 0.f; }
  for(int kp = 0; kp < 32; kp++){
    float2 f = F[kp][ol];
    #pragma unroll
    for(int u = 0; u < 16; u++){
      float2 t = twl[kp][mg*16 + u];
      re[u] += f.x*t.x - f.y*t.y;
      im[u] += f.x*t.y + f.y*t.x;
    }
  }
  int o = oh*32 + ol;
  #pragma unroll
  for(int u = 0; u < 16; u++){
    int m = mh*64 + mg*16 + u;
    T[((b*128 + m)*16 + ky)*64 + o] = make_float2(re[u], im[u]);
  }
}

// ---------------- Stage 5: hermitian inverse over ky (C2R), store bf16 -------
// T values preloaded into registers (pre-doubled); twiddles b64 broadcast.
__global__ __launch_bounds__(256) void k_inv2(const float2* __restrict__ T,
                                              const float2* __restrict__ TWY,
                                              bf16* __restrict__ XO,
                                              float* __restrict__ CZ){
  __shared__ float2 twl[16][128];
  int b = blockIdx.x >> 7, m = blockIdx.x & 127;
  int tid = threadIdx.x;
  int flat = blockIdx.x*256 + tid;
  if(flat < 16640) CZ[flat] = 0.f;      // zero Cg (16384) + SX (256)
  for(int idx = tid; idx < 2048; idx += 256)
    twl[idx >> 7][idx & 127] = TWY[idx];
  int o = tid & 63, ng = tid >> 6;
  const float2* tp = T + ((size_t)(b*128 + m)*16)*64 + o;
  float t0x = tp[0].x;
  float t2x[15], t2y[15];
  #pragma unroll
  for(int u = 0; u < 15; u++){
    float2 v = tp[(u + 1)*64];
    t2x[u] = 2.0f*v.x; t2y[u] = 2.0f*v.y;
  }
  __syncthreads();
  const float sc = 1.0f/128.0f;   // inverse ortho norm (both axes)
  for(int n = ng*32; n < ng*32 + 32; n++){
    float v = t0x;
    #pragma unroll
    for(int u = 0; u < 15; u++){
      float2 t = twl[u + 1][n];
      v += t2x[u]*t.x - t2y[u]*t.y;
    }
    XO[((b*128 + m)*128 + n)*64 + o] = __float2bfloat16(v*sc);
  }
}

// ------- Cov: S = X^T X (64x64) and sx = colsum(X) per b, via MFMA -----------
// grid 64: b = bi>>4, 1024-position chunk = bi&15 (4 sub-tiles of 256).
__global__ __launch_bounds__(256) void k_cov(const bf16* __restrict__ XO,
                                             float* __restrict__ Cg,
                                             float* __restrict__ SX){
  __shared__ short XT[64][264];    // [ch][pos], padded row
  __shared__ float sxl[64];
  int tid = threadIdx.x;
  int b = blockIdx.x >> 4, ck = blockIdx.x & 15;
  if(tid < 64) sxl[tid] = 0.f;
  float sxp[8];
  #pragma unroll
  for(int e = 0; e < 8; e++) sxp[e] = 0.f;
  int c0 = (tid & 7)*8;
  int lane = tid & 63, w = tid >> 6, l15 = lane & 15, quad = lane >> 4;
  f32x4 acc[4];
  #pragma unroll
  for(int tj = 0; tj < 4; tj++) acc[tj] = (f32x4){0.f,0.f,0.f,0.f};
  for(int st = 0; st < 4; st++){
    size_t pbase = (size_t)b*16384 + (size_t)ck*1024 + st*256;
    const short* xg = (const short*)XO + pbase*64;
    __syncthreads();
    for(int it = 0; it < 8; it++){
      int p = it*32 + (tid >> 3);
      short8 v = *(const short8*)(xg + (size_t)p*64 + c0);
      #pragma unroll
      for(int e = 0; e < 8; e++){
        XT[c0+e][p] = v[e];
        sxp[e] += s2f(v[e]);
      }
    }
    __syncthreads();
    for(int kk = 0; kk < 8; kk++){
      short8 a = *(const short8*)&XT[w*16 + l15][kk*32 + quad*8];
      #pragma unroll
      for(int tj = 0; tj < 4; tj++){
        short8 bfr = *(const short8*)&XT[tj*16 + l15][kk*32 + quad*8];
        acc[tj] = __builtin_amdgcn_mfma_f32_16x16x32_bf16(a, bfr, acc[tj], 0, 0, 0);
      }
    }
  }
  #pragma unroll
  for(int e = 0; e < 8; e++) atomicAdd(&sxl[c0+e], sxp[e]);
  __syncthreads();
  float* Cb = Cg + b*4096;
  #pragma unroll
  for(int tj = 0; tj < 4; tj++)
    #pragma unroll
    for(int r = 0; r < 4; r++)
      atomicAdd(&Cb[(w*16 + quad*4 + r)*64 + tj*16 + l15], acc[tj][r]);
  if(tid < 64) atomicAdd(&SX[b*64 + tid], sxl[tid]);
}

// ------- Stat: GN1 group sums from quadratic form; writes S1 directly --------
__global__ __launch_bounds__(256) void k_stat(const float* __restrict__ Cg,
                                              const float* __restrict__ SX,
                                              const short* __restrict__ W1g,
                                              const float* __restrict__ PB,
                                              float* __restrict__ ST){
  __shared__ float Cl[64][65];
  __shared__ float Wl[16][64];
  __shared__ float sxl[64];
  __shared__ float g2[2];
  int tid = threadIdx.x;
  int br = blockIdx.x >> 6, b = (blockIdx.x >> 4) & 3, g = blockIdx.x & 15;
  const float* Cb = Cg + b*4096;
  for(int u = tid; u < 4096; u += 256) Cl[u >> 6][u & 63] = Cb[u];
  const short* W1 = W1g + br*16384;
  for(int u = tid; u < 1024; u += 256){
    int nl = u >> 6, k = u & 63;
    int n = g*16 + nl;
    int fid = ((n >> 6)*4 + ((n >> 4) & 3))*2 + (k >> 5);
    int lane = ((k >> 3) & 3)*16 + (n & 15);
    Wl[nl][k] = s2f(W1[fid*512 + lane*8 + (k & 7)]);
  }
  if(tid < 64) sxl[tid] = SX[b*64 + tid];
  if(tid < 2) g2[tid] = 0.f;
  __syncthreads();
  int nl = tid >> 4, ic = tid & 15;
  float qa = 0.f, sa = 0.f;
  for(int io = 0; io < 4; io++){
    int i = ic*4 + io;
    float wi = Wl[nl][i];
    float dot = 0.f;
    #pragma unroll 8
    for(int j = 0; j < 64; j++) dot += Cl[i][j]*Wl[nl][j];
    qa += wi*dot;
    sa += wi*sxl[i];
  }
  for(int off = 8; off; off >>= 1){
    qa += __shfl_xor(qa, off);
    sa += __shfl_xor(sa, off);
  }
  if(ic == 0){
    float bn = PB[br*2048 + g*16 + nl];
    float hs = sa + 16384.f*bn;
    float hq = qa + 2.f*bn*sa + 16384.f*bn*bn;
    atomicAdd(&g2[0], hs); atomicAdd(&g2[1], hq);
  }
  __syncthreads();
  if(tid == 0){
    float* S1 = ST + br*192;
    S1[(b*16 + g)*2]     = g2[0];
    S1[(b*16 + g)*2 + 1] = g2[1];
  }
}

// ------- FF main: GEMM1+GN1+relu+GEMM2 -> h2 fp32 + per-channel sums ---------
// Also reads z and accumulates per-channel {Sh, Sh2, Sz, Sz2, Shz} so the
// GN2->GN3 chain reduces to a tiny stats kernel + one fused affine pass.
__global__ __launch_bounds__(256, 2) void k_ffmain(const bf16* __restrict__ XO,
                                                   const short* __restrict__ W1g,
                                                   const short* __restrict__ W2g,
                                                   const float* __restrict__ PB,
                                                   const float* __restrict__ ST,
                                                   const float* __restrict__ z,
                                                   float* __restrict__ CS,
                                                   float* __restrict__ out){
  __shared__ short Ws1[16384];     // 32KB frag-order W1
  __shared__ short Ws2[16384];     // 32KB frag-order W2
  __shared__ short Hn[64][72];     // per-wave-private row slices
  __shared__ float mu1[16], rs1[16];
  __shared__ float cs[5][64];      // per-channel partial sums
  int tid = threadIdx.x;
  int br = blockIdx.x >> 8, rb = blockIdx.x & 255;
  int r0 = rb << 8, b = rb >> 6;
  const float* pb = PB + br*2048;
  {
    const uint4* g1 = (const uint4*)(W1g + br*16384);
    const uint4* g2w = (const uint4*)(W2g + br*16384);
    uint4* s1 = (uint4*)Ws1; uint4* s2 = (uint4*)Ws2;
    #pragma unroll
    for(int u = 0; u < 8; u++){
      s1[u*256 + tid] = g1[u*256 + tid];
      s2[u*256 + tid] = g2w[u*256 + tid];
    }
  }
  if(tid < 16){
    const float cnt = 262144.f;  // 128*128*16
    const float* S1 = ST + br*192;
    float s = S1[(b*16 + tid)*2], q = S1[(b*16 + tid)*2 + 1];
    float mean = s/cnt, var = q/cnt - mean*mean;
    mu1[tid] = mean; rs1[tid] = rsqrtf(fmaxf(var, 0.f) + EPSV);
  }
  {
    float* c1 = &cs[0][0];
    c1[tid] = 0.f;
    if(tid < 64) c1[256 + tid] = 0.f;
  }
  __syncthreads();
  int lane = tid & 63, w = tid >> 6, l15 = lane & 15, quad = lane >> 4;
  int myrow = w*16 + l15;
  float sh[4]  = {0,0,0,0}, sh2[4] = {0,0,0,0};
  float sz[4]  = {0,0,0,0}, sz2[4] = {0,0,0,0}, shz[4] = {0,0,0,0};
  for(int c = 0; c < 4; c++){
    const short* xop = (const short*)XO + ((size_t)(r0 + c*64 + myrow))*64;
    short8 a0 = *(const short8*)(xop + quad*8);
    short8 a1 = *(const short8*)(xop + 32 + quad*8);
    f32x4 acc2[4];
    #pragma unroll
    for(int t = 0; t < 4; t++) acc2[t] = (f32x4){0.f,0.f,0.f,0.f};
    for(int ch = 0; ch < 4; ch++){
      #pragma unroll
      for(int t = 0; t < 4; t++){
        int fid = (ch*4 + t)*2;
        short8 b0 = *(const short8*)(Ws1 + fid*512 + lane*8);
        short8 b1 = *(const short8*)(Ws1 + fid*512 + 512 + lane*8);
        f32x4 acc = {0.f,0.f,0.f,0.f};
        acc = __builtin_amdgcn_mfma_f32_16x16x32_bf16(a0, b0, acc, 0, 0, 0);
        acc = __builtin_amdgcn_mfma_f32_16x16x32_bf16(a1, b1, acc, 0, 0, 0);
        int n = ch*64 + t*16 + l15, gi = n >> 4;
        float w1v = pb[256 + n];
        float gwv = w1v * rs1[gi];
        float gbv = (pb[n] - mu1[gi])*rs1[gi]*w1v + pb[512 + n];
        #pragma unroll
        for(int r = 0; r < 4; r++){
          float hv = acc[r]*gwv + gbv;
          hv = hv > 0.f ? hv : 0.f;
          Hn[w*16 + quad*4 + r][t*16 + l15] = f2bs(hv);
        }
      }
      short8 ha0 = *(short8*)&Hn[myrow][quad*8];
      short8 ha1 = *(short8*)&Hn[myrow][32 + quad*8];
      #pragma unroll
      for(int t = 0; t < 4; t++){
        int fid = (ch*4 + t)*2;
        short8 b0 = *(const short8*)(Ws2 + fid*512 + lane*8);
        short8 b1 = *(const short8*)(Ws2 + fid*512 + 512 + lane*8);
        acc2[t] = __builtin_amdgcn_mfma_f32_16x16x32_bf16(ha0, b0, acc2[t], 0, 0, 0);
        acc2[t] = __builtin_amdgcn_mfma_f32_16x16x32_bf16(ha1, b1, acc2[t], 0, 0, 0);
      }
    }
    size_t obase_off = ((size_t)(b*2 + br)*16384 + (r0 & 16383) + c*64)*64;
    float* obase = out + obase_off;
    const float* zbase = z + obase_off;
    #pragma unroll
    for(int t = 0; t < 4; t++){
      int col = t*16 + l15;
      float bias2 = pb[768 + col];
      #pragma unroll
      for(int r = 0; r < 4; r++){
        size_t off = (size_t)(w*16 + quad*4 + r)*64 + col;
        float h2 = acc2[t][r] + bias2;
        float zv = zbase[off];
        obase[off] = h2;
        sh[t] += h2; sh2[t] += h2*h2;
        sz[t] += zv; sz2[t] += zv*zv; shz[t] += h2*zv;
      }
    }
  }
  #pragma unroll
  for(int t = 0; t < 4; t++){
    float v0 = sh[t], v1 = sh2[t], v2 = sz[t], v3 = sz2[t], v4 = shz[t];
    v0 += __shfl_xor(v0, 16); v0 += __shfl_xor(v0, 32);
    v1 += __shfl_xor(v1, 16); v1 += __shfl_xor(v1, 32);
    v2 += __shfl_xor(v2, 16); v2 += __shfl_xor(v2, 32);
    v3 += __shfl_xor(v3, 16); v3 += __shfl_xor(v3, 32);
    v4 += __shfl_xor(v4, 16); v4 += __shfl_xor(v4, 32);
    if(quad == 0){
      int ch = t*16 + l15;
      atomicAdd(&cs[0][ch], v0); atomicAdd(&cs[1][ch], v1);
      atomicAdd(&cs[2][ch], v2); atomicAdd(&cs[3][ch], v3);
      atomicAdd(&cs[4][ch], v4);
    }
  }
  __syncthreads();
  float* slab = CS + (size_t)blockIdx.x*320;
  const float* c1 = &cs[0][0];
  slab[tid] = c1[tid];
  if(tid < 64) slab[256 + tid] = c1[256 + tid];
}

// ------- StatB: GN2 params + analytic GN3 stats -> fused affine coeffs -------
// grid 8 (br,b). final = alpha*h2 + beta*z + gamma.
__global__ __launch_bounds__(256) void k_statB(const float* __restrict__ CS,
                                               const float* __restrict__ PB,
                                               float* __restrict__ CF){
  __shared__ float chs[5][64];
  __shared__ float mu2s[4], rs2s[4], tg[4], tq[4], mu3s[4], rs3s[4];
  int br = blockIdx.x >> 2, b = blockIdx.x & 3;
  int tid = threadIdx.x;
  const float* base = CS + ((size_t)(br*256 + b*64))*320;
  float* c1 = &chs[0][0];
  for(int v = tid; v < 320; v += 256){
    float s = 0.f;
    for(int k = 0; k < 64; k++) s += base[(size_t)k*320 + v];
    c1[v] = s;
  }
  __syncthreads();
  if(tid < 4){
    float s = 0.f, q = 0.f;
    for(int o = tid*16; o < tid*16 + 16; o++){ s += chs[0][o]; q += chs[1][o]; }
    float mean = s/262144.f, var = q/262144.f - mean*mean;
    mu2s[tid] = mean; rs2s[tid] = rsqrtf(fmaxf(var, 0.f) + EPSV);
    tg[tid] = 0.f; tq[tid] = 0.f;
  }
  __syncthreads();
  const float* pb = PB + br*2048;
  if(tid < 64){
    int o = tid, g = o >> 4;
    float w2v = pb[832 + o], b2v = pb[896 + o];
    float gw = w2v*rs2s[g], gb = b2v - mu2s[g]*rs2s[g]*w2v;
    float Sh = chs[0][o], Sh2 = chs[1][o], Sz = chs[2][o], Sz2 = chs[3][o], Shz = chs[4][o];
    float st = gw*Sh + Sz + 16384.f*gb;
    float sq = gw*gw*Sh2 + Sz2 + 16384.f*gb*gb + 2.f*gw*Shz + 2.f*gw*gb*Sh + 2.f*gb*Sz;
    atomicAdd(&tg[g], st); atomicAdd(&tq[g], sq);
  }
  __syncthreads();
  if(tid < 4){
    float mean = tg[tid]/262144.f, var = tq[tid]/262144.f - mean*mean;
    mu3s[tid] = mean; rs3s[tid] = rsqrtf(fmaxf(var, 0.f) + EPSV);
  }
  __syncthreads();
  if(tid < 64){
    int o = tid, g = o >> 4;
    float w2v = pb[832 + o], b2v = pb[896 + o];
    float gw = w2v*rs2s[g], gb = b2v - mu2s[g]*rs2s[g]*w2v;
    float w3v = pb[960 + o], b3v = pb[1024 + o];
    float gw3 = w3v*rs3s[g], gb3 = b3v - mu3s[g]*rs3s[g]*w3v;
    float* cf = CF + (size_t)(br*4 + b)*192;
    cf[o]       = gw*gw3;          // alpha (h2 coefficient)
    cf[64 + o]  = gw3;             // beta  (z coefficient)
    cf[128 + o] = gb*gw3 + gb3;    // gamma
  }
}

// ------- Final: out = alpha*h2 + beta*z + gamma, float4, in place ------------
__global__ __launch_bounds__(256) void k_final(const float* __restrict__ z,
                                               const float* __restrict__ CF,
                                               float* __restrict__ out){
  int tid = blockIdx.x*256 + threadIdx.x;
  const float4* z4 = (const float4*)z;
  const float4* cf4 = (const float4*)CF;
  float4* o4 = (float4*)out;
  #pragma unroll
  for(int r = 0; r < 8; r++){
    int i4 = r*262144 + tid;
    int s = i4 >> 18;                 // (b*2+br)
    int b = s >> 1, br = s & 1;
    int cbase = (br*4 + b)*48 + (i4 & 15);
    float4 a = cf4[cbase], bb = cf4[cbase + 16], g = cf4[cbase + 32];
    float4 h = o4[i4], zv = z4[i4];
    o4[i4] = make_float4(h.x*a.x + zv.x*bb.x + g.x,
                         h.y*a.y + zv.y*bb.y + g.y,
                         h.z*a.z + zv.z*bb.z + g.z,
                         h.w*a.w + zv.w*bb.w + g.w);
  }
}

extern "C" void kernel_launch(void* const* d_in, const int* in_sizes, int n_in,
                              void* d_out, int out_size, void* d_ws, size_t ws_size,
                              hipStream_t stream){
  const float* z   = (const float*)d_in[0];
  const float* x   = (const float*)d_in[1];
  const float* fw1 = (const float*)d_in[2];
  const float* fw2 = (const float*)d_in[3];
  char* ws = (char*)d_ws;
  // workspace layout (byte offsets)
  float2* Y   = (float2*)(ws + 0);           // 4,194,304 B
  float2* X2  = (float2*)(ws + 4194304);     // 1,048,576 B
  float2* T   = Y;                           // alias: Y dead after k_xdft
  bf16*   XO  = (bf16*)(ws + 5242880);       // 8,388,608 B
  float*  ST  = (float*)(ws + 13631488);     // 2,048 B
  short*  W1g = (short*)(ws + 13633536);     // 65,536 B
  short*  W2g = (short*)(ws + 13699072);     // 65,536 B
  float2* TWY = (float2*)(ws + 13764608);    // 16,384 B
  float2* TWX = (float2*)(ws + 13780992);    // 32,768 B
  float*  PB  = (float*)(ws + 13813760);     // 16,384 B
  float2* FWT = (float2*)(ws + 13830144);    // 16,777,216 B -> ends 30,607,360
  // Aliases into the FWT region (FWT dead after k_mix):
  float*  Cg  = (float*)(ws + 13830144);     // 65,536 B  (4 x 64 x 64), zeroed in k_inv2
  float*  SX  = Cg + 16384;                  // 1,024 B   (4 x 64), zeroed in k_inv2
  float*  CS  = (float*)(ws + 14878720);     // 655,360 B (512 slabs x 320)
  float*  CF  = (float*)(ws + 15927296);     // 6,144 B   (8 x 192)

  const float* p[20];
  for(int i = 0; i < 20; i++) p[i] = (const float*)d_in[4 + i];

  k_prep<<<802, 256, 0, stream>>>(fw1, fw2, FWT,
                                  p[0],p[1],p[2],p[3],p[4],p[5],p[6],p[7],p[8],p[9],
                                  p[10],p[11],p[12],p[13],p[14],p[15],p[16],p[17],p[18],p[19],
                                  W1g, W2g, TWY, TWX, PB, ST);
  k_ydft<<<512, 256, 0, stream>>>(x, z, TWY, Y);
  k_xdft<<<256, 128, 0, stream>>>(Y, TWX, X2);
  k_mix<<<128, 256, 0, stream>>>(X2, FWT);
  k_inv1<<<256, 128, 0, stream>>>(X2, TWX, T);
  k_inv2<<<512, 256, 0, stream>>>(T, TWY, XO, Cg);
  k_cov<<<64, 256, 0, stream>>>(XO, Cg, SX);
  k_stat<<<128, 256, 0, stream>>>(Cg, SX, W1g, PB, ST);
  k_ffmain<<<512, 256, 0, stream>>>(XO, W1g, W2g, PB, ST, z, CS, (float*)d_out);
  k_statB<<<8, 256, 0, stream>>>(CS, PB, CF);
  k_final<<<1024, 256, 0, stream>>>(z, CF, (float*)d_out);
}

// Round 3
// 261.710 us; speedup vs baseline: 1.5806x; 1.1442x over previous
//
#include <hip/hip_runtime.h>
#include <hip/hip_bf16.h>

typedef __hip_bfloat16 bf16;
typedef __attribute__((ext_vector_type(8))) short short8;   // 8 bf16 (4 VGPRs)
typedef __attribute__((ext_vector_type(4))) float f32x4;    // 4 fp32 acc

#define PI2 6.283185307179586f
#define EPSV 1e-5f

__device__ __forceinline__ short f2bs(float f){
  bf16 h = __float2bfloat16(f);
  short s; __builtin_memcpy(&s, &h, 2); return s;
}
__device__ __forceinline__ float s2f(short s){
  bf16 h; __builtin_memcpy(&h, &s, 2); return __bfloat162float(h);
}
__device__ __forceinline__ float4 f4add(float4 a, float4 b){ return make_float4(a.x+b.x, a.y+b.y, a.z+b.z, a.w+b.w); }
__device__ __forceinline__ float4 f4sub(float4 a, float4 b){ return make_float4(a.x-b.x, a.y-b.y, a.z-b.z, a.w-b.w); }

// ---------------- Prep (merged): fw transpose + weights/params/twiddles ------
__global__ __launch_bounds__(256) void k_prep(
    const float* __restrict__ fw1, const float* __restrict__ fw2,
    float2* __restrict__ FWT,
    const float* __restrict__ b_l1w, const float* __restrict__ b_l1b,
    const float* __restrict__ b_l2w, const float* __restrict__ b_l2b,
    const float* __restrict__ b_g1w, const float* __restrict__ b_g1b,
    const float* __restrict__ b_g2w, const float* __restrict__ b_g2b,
    const float* __restrict__ b_g3w, const float* __restrict__ b_g3b,
    const float* __restrict__ f_l1w, const float* __restrict__ f_l1b,
    const float* __restrict__ f_l2w, const float* __restrict__ f_l2b,
    const float* __restrict__ f_g1w, const float* __restrict__ f_g1b,
    const float* __restrict__ f_g2w, const float* __restrict__ f_g2b,
    const float* __restrict__ f_g3w, const float* __restrict__ f_g3b,
    short* __restrict__ W1g, short* __restrict__ W2g,
    float2* __restrict__ TWY, float2* __restrict__ TWX,
    float* __restrict__ PB, float* __restrict__ ST){
  __shared__ float Ls[16][512];
  int tid = threadIdx.x;
  if(blockIdx.x < 512){
    int arr = blockIdx.x >> 8, rem = blockIdx.x & 255;
    int i = rem >> 2, o0 = (rem & 3) * 16;
    const float* src = (arr ? fw2 : fw1) + ((size_t)(i*64 + o0))*512;
    for(int idx = tid; idx < 8192; idx += 256)
      Ls[idx >> 9][idx & 511] = src[idx];
    __syncthreads();
    int kxw = tid >> 4, ky = tid & 15;
    float2* dst = FWT + ((size_t)((arr*16 + kxw)*16 + ky))*4096 + i*64 + o0;
    for(int ol = 0; ol < 16; ol++)
      dst[ol] = make_float2(Ls[ol][tid*2], Ls[ol][tid*2 + 1]);
    return;
  }
  int i = (blockIdx.x - 512)*256 + tid;
  if(i < 32768){                         // W1g fragment layout
    int br = i >> 14, r = i & 16383;
    int fid = r >> 9, lane = (r >> 3) & 63, e = r & 7;
    int hb = fid & 1, t = (fid >> 1) & 3, ch = fid >> 3;
    int l15 = lane & 15, quad = lane >> 4;
    int n = ch*64 + t*16 + l15;
    int k = hb*32 + quad*8 + e;
    const float* src = br ? f_l1w : b_l1w;
    W1g[i] = f2bs(src[k*256 + n]);
    return;
  }
  i -= 32768;
  if(i < 32768){                         // W2g fragment layout
    int br = i >> 14, r = i & 16383;
    int fid = r >> 9, lane = (r >> 3) & 63, e = r & 7;
    int hb = fid & 1, t = (fid >> 1) & 3, ch = fid >> 3;
    int l15 = lane & 15, quad = lane >> 4;
    int n = t*16 + l15;
    int k = ch*64 + hb*32 + quad*8 + e;
    const float* src = br ? f_l2w : b_l2w;
    W2g[i] = f2bs(src[k*64 + n]);
    return;
  }
  i -= 32768;
  if(i < 2048){                          // TWY[ky][n]
    int ky = i >> 7, n = i & 127;
    float ang = PI2 * (float)((ky*n) & 127) / 128.0f;
    float s, c; sincosf(ang, &s, &c);
    TWY[i] = make_float2(c, s);
    return;
  }
  i -= 2048;
  if(i < 4096){                          // TWX[kp][m]
    int kp = i >> 7, m = i & 127;
    int kx = kp < 16 ? kp : 96 + kp;
    float ang = PI2 * (float)((kx*m) & 127) / 128.0f;
    float s, c; sincosf(ang, &s, &c);
    TWX[i] = make_float2(c, s);
    return;
  }
  i -= 4096;
  if(i < 384){ ST[i] = 0.f; return; }    // zero stats
  i -= 384;
  if(i < 2176){                          // param block
    int br = i >= 1088; int o = i - br*1088;
    float* pb = PB + br*2048;
    float v;
    if(o < 256)       v = (br ? f_l1b : b_l1b)[o];
    else if(o < 512)  v = (br ? f_g1w : b_g1w)[o-256];
    else if(o < 768)  v = (br ? f_g1b : b_g1b)[o-512];
    else if(o < 832)  v = (br ? f_l2b : b_l2b)[o-768];
    else if(o < 896)  v = (br ? f_g2w : b_g2w)[o-832];
    else if(o < 960)  v = (br ? f_g2b : b_g2b)[o-896];
    else if(o < 1024) v = (br ? f_g3w : b_g3w)[o-960];
    else              v = (br ? f_g3b : b_g3b)[o-1024];
    pb[o] = v;
  }
}

// ---------------- Stage 1: x4 = x - backcast; DFT over y, radix-4 over n -----
// tw[ky][n'+32q] = tw[ky][n']*(-i)^(ky*q); ky = kq*4+j so residue r == j.
// G0 = P (real), G1 = R - iS, G2 = Q (real), G3 = R + iS.
__global__ __launch_bounds__(256) void k_ydft(const float* __restrict__ x,
                                              const float* __restrict__ z,
                                              const float2* __restrict__ TWY,
                                              float2* __restrict__ Y){
  __shared__ float P[32][64], Q[32][64], R[32][64], S[32][64];
  __shared__ float2 twl[16][32];
  int b = blockIdx.x >> 7, m = blockIdx.x & 127;
  int tid = threadIdx.x;
  const float4* xp = (const float4*)(x + ((size_t)(b*128 + m)*128)*64);
  const float4* zp = (const float4*)(z + ((size_t)((b*2 + 0)*128 + m)*128)*64);
  int i4 = tid & 15, n0 = tid >> 4;
  #pragma unroll
  for(int it = 0; it < 2; it++){
    int np = n0 + it*16;
    float4 ea = f4sub(xp[np*16 + i4],      zp[np*16 + i4]);
    float4 eb = f4sub(xp[(np+32)*16 + i4], zp[(np+32)*16 + i4]);
    float4 ec = f4sub(xp[(np+64)*16 + i4], zp[(np+64)*16 + i4]);
    float4 ed = f4sub(xp[(np+96)*16 + i4], zp[(np+96)*16 + i4]);
    float4 sum_ac = f4add(ea, ec), sum_bd = f4add(eb, ed);
    *(float4*)&P[np][i4*4] = f4add(sum_ac, sum_bd);
    *(float4*)&Q[np][i4*4] = f4sub(sum_ac, sum_bd);
    *(float4*)&R[np][i4*4] = f4sub(ea, ec);
    *(float4*)&S[np][i4*4] = f4sub(eb, ed);
  }
  for(int idx = tid; idx < 512; idx += 256)
    twl[idx >> 5][idx & 31] = TWY[(idx >> 5)*128 + (idx & 31)];
  __syncthreads();
  int i = tid & 63, kq = tid >> 6;
  float re[4] = {0,0,0,0}, im[4] = {0,0,0,0};
  for(int np = 0; np < 32; np++){
    float p = P[np][i], q = Q[np][i], r = R[np][i], s = S[np][i];
    float2 t0 = twl[kq*4 + 0][np];
    float2 t1 = twl[kq*4 + 1][np];
    float2 t2 = twl[kq*4 + 2][np];
    float2 t3 = twl[kq*4 + 3][np];
    re[0] += p*t0.x;            im[0] -= p*t0.y;
    re[1] += r*t1.x - s*t1.y;   im[1] -= s*t1.x + r*t1.y;
    re[2] += q*t2.x;            im[2] -= q*t2.y;
    re[3] += r*t3.x + s*t3.y;   im[3] += s*t3.x - r*t3.y;
  }
  #pragma unroll
  for(int j = 0; j < 4; j++)
    Y[((b*128 + m)*16 + kq*4 + j)*64 + i] = make_float2(re[j], im[j]);
}

// ------- Stage 2: DFT over x, radix-2 over m + split-m partial sums ----------
// tw[kp][m+64] = tw[kp][m]*(-1)^kx, kx parity == kpl parity == j parity.
__global__ __launch_bounds__(256) void k_xdft(const float2* __restrict__ Y,
                                              const float2* __restrict__ TWX,
                                              float2* __restrict__ X2){
  __shared__ float2 twl[16][64];
  __shared__ float sc[128][8];
  int bi = blockIdx.x;
  int b = bi >> 6, ky = (bi >> 2) & 15, half = (bi >> 1) & 1, ih = bi & 1;
  int tid = threadIdx.x;
  for(int idx = tid; idx < 1024; idx += 256)
    twl[idx >> 6][idx & 63] = TWX[(half*16 + (idx >> 6))*128 + (idx & 63)];
  __syncthreads();
  int i = ih*32 + (tid & 31), grp = (tid >> 5) & 3, mh2 = tid >> 7;
  const float2* yb = Y + (size_t)b*131072 + ky*64 + i;
  float re[4] = {0,0,0,0}, im[4] = {0,0,0,0};
  for(int mi = 0; mi < 32; mi++){
    int mp = mh2*32 + mi;
    float2 y1 = yb[(size_t)mp*1024];
    float2 y2 = yb[(size_t)(mp + 64)*1024];
    float2 ye = make_float2(y1.x + y2.x, y1.y + y2.y);
    float2 yo = make_float2(y1.x - y2.x, y1.y - y2.y);
    float2 t0 = twl[grp*4 + 0][mp];
    float2 t1 = twl[grp*4 + 1][mp];
    float2 t2 = twl[grp*4 + 2][mp];
    float2 t3 = twl[grp*4 + 3][mp];
    re[0] += ye.x*t0.x + ye.y*t0.y;  im[0] += ye.y*t0.x - ye.x*t0.y;
    re[1] += yo.x*t1.x + yo.y*t1.y;  im[1] += yo.y*t1.x - yo.x*t1.y;
    re[2] += ye.x*t2.x + ye.y*t2.y;  im[2] += ye.y*t2.x - ye.x*t2.y;
    re[3] += yo.x*t3.x + yo.y*t3.y;  im[3] += yo.y*t3.x - yo.x*t3.y;
  }
  if(mh2){
    int sl = tid & 127;
    #pragma unroll
    for(int j = 0; j < 4; j++){ sc[sl][j] = re[j]; sc[sl][4 + j] = im[j]; }
  }
  __syncthreads();
  if(!mh2){
    const float scn = 1.0f/128.0f;   // forward ortho norm (both axes)
    #pragma unroll
    for(int j = 0; j < 4; j++){
      float rr = (re[j] + sc[tid][j])*scn;
      float ii = (im[j] + sc[tid][4 + j])*scn;
      int kp = half*16 + grp*4 + j;
      X2[((b*32 + kp)*16 + ky)*64 + i] = make_float2(rr, ii);
    }
  }
}

// ------- Stage 3: per-mode 64x64 complex mix, 2 p/block + i-split ------------
__global__ __launch_bounds__(256) void k_mix(float2* __restrict__ X2,
                                             const float2* __restrict__ FWT){
  __shared__ float2 Xs[2][4][64];   // [pair_local][batch][i]
  __shared__ float sc[2][64][8];
  int tid = threadIdx.x;
  for(int idx = tid; idx < 512; idx += 256){
    int pl = idx >> 8, b = (idx >> 6) & 3, i = idx & 63;
    int p = blockIdx.x*2 + pl; int kp = p >> 4, ky = p & 15;
    Xs[pl][b][i] = X2[((b*32 + kp)*16 + ky)*64 + i];
  }
  __syncthreads();
  int o = tid & 63, w = tid >> 6, pl = w >> 1, ih = w & 1;
  int p = blockIdx.x*2 + pl; int kp = p >> 4, ky = p & 15;
  int arr = kp < 16 ? 0 : 1, kxw = kp < 16 ? kp : kp - 16;
  const float2* wp = FWT + ((size_t)((arr*16 + kxw)*16 + ky))*4096;
  float rr[4] = {0,0,0,0}, ii[4] = {0,0,0,0};
  for(int i = ih*32; i < ih*32 + 32; i++){
    float2 wv = wp[i*64 + o];
    #pragma unroll
    for(int b = 0; b < 4; b++){
      float xr = Xs[pl][b][i].x, xi = Xs[pl][b][i].y;
      rr[b] += xr*wv.x - xi*wv.y;
      ii[b] += xr*wv.y + xi*wv.x;
    }
  }
  if(ih){
    #pragma unroll
    for(int b = 0; b < 4; b++){ sc[pl][o][b*2] = rr[b]; sc[pl][o][b*2 + 1] = ii[b]; }
  }
  __syncthreads();
  if(!ih){
    #pragma unroll
    for(int b = 0; b < 4; b++){
      float r2 = rr[b] + sc[pl][o][b*2], i2 = ii[b] + sc[pl][o][b*2 + 1];
      X2[((b*32 + kp)*16 + ky)*64 + o] = make_float2(r2, i2);
    }
  }
}

// ------- Stage 4: inverse DFT over kx, radix-2 over m (E/O accumulators) -----
// out[m'] = E+O, out[m'+64] = E-O; parity of kx == parity of kp.
__global__ __launch_bounds__(256) void k_inv1(const float2* __restrict__ OF,
                                              const float2* __restrict__ TWX,
                                              float2* __restrict__ T){
  __shared__ float2 Fl[32][16];
  __shared__ float2 twl[32][64];
  int bi = blockIdx.x;
  int b = bi >> 6, ky = (bi >> 2) & 15, oq = bi & 3;
  int tid = threadIdx.x;
  for(int idx = tid; idx < 512; idx += 256){
    int kp = idx >> 4, ol = idx & 15;
    Fl[kp][ol] = OF[((b*32 + kp)*16 + ky)*64 + oq*16 + ol];
  }
  for(int idx = tid; idx < 2048; idx += 256){
    int kp = idx >> 6, ml = idx & 63;
    twl[kp][ml] = TWX[kp*128 + ml];
  }
  __syncthreads();
  int ol = tid & 15, mg = tid >> 4;     // mg in [0,16)
  float reE[4] = {0,0,0,0}, imE[4] = {0,0,0,0};
  float reO[4] = {0,0,0,0}, imO[4] = {0,0,0,0};
  for(int kp = 0; kp < 32; kp += 2){
    float2 fe = Fl[kp][ol], fo = Fl[kp + 1][ol];
    #pragma unroll
    for(int u = 0; u < 4; u++){
      float2 te = twl[kp][mg*4 + u], to = twl[kp + 1][mg*4 + u];
      reE[u] += fe.x*te.x - fe.y*te.y;
      imE[u] += fe.x*te.y + fe.y*te.x;
      reO[u] += fo.x*to.x - fo.y*to.y;
      imO[u] += fo.x*to.y + fo.y*to.x;
    }
  }
  int o = oq*16 + ol;
  #pragma unroll
  for(int u = 0; u < 4; u++){
    int ml = mg*4 + u;
    T[((b*128 + ml)*16 + ky)*64 + o]      = make_float2(reE[u] + reO[u], imE[u] + imO[u]);
    T[((b*128 + ml + 64)*16 + ky)*64 + o] = make_float2(reE[u] - reO[u], imE[u] - imO[u]);
  }
}

// ---------- Stage 5: hermitian C2R over ky, radix-2 over n, 2 m/block --------
// out[n'] = A+B, out[n'+64] = A-B (A = even-ky terms incl DC, B = odd-ky).
__global__ __launch_bounds__(256) void k_inv2(const float2* __restrict__ T,
                                              const float2* __restrict__ TWY,
                                              bf16* __restrict__ XO,
                                              float* __restrict__ CZ){
  __shared__ float2 twl[16][64];
  int b = blockIdx.x >> 6, mp = blockIdx.x & 63;
  int m0 = mp*2, m1 = m0 + 1;
  int tid = threadIdx.x;
  int flat = blockIdx.x*256 + tid;
  if(flat < 16640) CZ[flat] = 0.f;      // zero Cg (16384) + SX (256)
  for(int idx = tid; idx < 1024; idx += 256)
    twl[idx >> 6][idx & 63] = TWY[(idx >> 6)*128 + (idx & 63)];
  int o = tid & 63, ng = tid >> 6;
  const float2* tp0 = T + ((size_t)(b*128 + m0)*16)*64 + o;
  const float2* tp1 = T + ((size_t)(b*128 + m1)*16)*64 + o;
  float t0a = tp0[0].x, t0b = tp1[0].x;
  float ax[15], ay[15], bx2[15], by2[15];
  #pragma unroll
  for(int u = 0; u < 15; u++){
    float2 v0 = tp0[(u + 1)*64]; ax[u]  = 2.f*v0.x; ay[u]  = 2.f*v0.y;
    float2 v1 = tp1[(u + 1)*64]; bx2[u] = 2.f*v1.x; by2[u] = 2.f*v1.y;
  }
  __syncthreads();
  const float scn = 1.0f/128.0f;   // inverse ortho norm (both axes)
  bf16* xo0 = XO + ((size_t)(b*128 + m0)*128)*64 + o;
  bf16* xo1 = XO + ((size_t)(b*128 + m1)*128)*64 + o;
  for(int np = ng*16; np < ng*16 + 16; np++){
    float A0 = t0a, B0 = 0.f, A1 = t0b, B1 = 0.f;
    #pragma unroll
    for(int u = 0; u < 15; u++){   // ky = u+1; even ky <=> odd u
      float2 t = twl[u + 1][np];
      float pr0 = ax[u]*t.x  - ay[u]*t.y;
      float pr1 = bx2[u]*t.x - by2[u]*t.y;
      if(u & 1){ A0 += pr0; A1 += pr1; }
      else     { B0 += pr0; B1 += pr1; }
    }
    xo0[(size_t)np*64]        = __float2bfloat16((A0 + B0)*scn);
    xo0[(size_t)(np + 64)*64] = __float2bfloat16((A0 - B0)*scn);
    xo1[(size_t)np*64]        = __float2bfloat16((A1 + B1)*scn);
    xo1[(size_t)(np + 64)*64] = __float2bfloat16((A1 - B1)*scn);
  }
}

// ------- Cov: S = X^T X (64x64) and sx = colsum(X) per b, via MFMA -----------
__global__ __launch_bounds__(256) void k_cov(const bf16* __restrict__ XO,
                                             float* __restrict__ Cg,
                                             float* __restrict__ SX){
  __shared__ short XT[64][264];    // [ch][pos], padded row
  __shared__ float sxl[64];
  int tid = threadIdx.x;
  int b = blockIdx.x >> 4, ck = blockIdx.x & 15;
  if(tid < 64) sxl[tid] = 0.f;
  float sxp[8];
  #pragma unroll
  for(int e = 0; e < 8; e++) sxp[e] = 0.f;
  int c0 = (tid & 7)*8;
  int lane = tid & 63, w = tid >> 6, l15 = lane & 15, quad = lane >> 4;
  f32x4 acc[4];
  #pragma unroll
  for(int tj = 0; tj < 4; tj++) acc[tj] = (f32x4){0.f,0.f,0.f,0.f};
  for(int st = 0; st < 4; st++){
    size_t pbase = (size_t)b*16384 + (size_t)ck*1024 + st*256;
    const short* xg = (const short*)XO + pbase*64;
    __syncthreads();
    for(int it = 0; it < 8; it++){
      int p = it*32 + (tid >> 3);
      short8 v = *(const short8*)(xg + (size_t)p*64 + c0);
      #pragma unroll
      for(int e = 0; e < 8; e++){
        XT[c0+e][p] = v[e];
        sxp[e] += s2f(v[e]);
      }
    }
    __syncthreads();
    for(int kk = 0; kk < 8; kk++){
      short8 a = *(const short8*)&XT[w*16 + l15][kk*32 + quad*8];
      #pragma unroll
      for(int tj = 0; tj < 4; tj++){
        short8 bfr = *(const short8*)&XT[tj*16 + l15][kk*32 + quad*8];
        acc[tj] = __builtin_amdgcn_mfma_f32_16x16x32_bf16(a, bfr, acc[tj], 0, 0, 0);
      }
    }
  }
  #pragma unroll
  for(int e = 0; e < 8; e++) atomicAdd(&sxl[c0+e], sxp[e]);
  __syncthreads();
  float* Cb = Cg + b*4096;
  #pragma unroll
  for(int tj = 0; tj < 4; tj++)
    #pragma unroll
    for(int r = 0; r < 4; r++)
      atomicAdd(&Cb[(w*16 + quad*4 + r)*64 + tj*16 + l15], acc[tj][r]);
  if(tid < 64) atomicAdd(&SX[b*64 + tid], sxl[tid]);
}

// ------- Stat: GN1 group sums from quadratic form; writes S1 directly --------
__global__ __launch_bounds__(256) void k_stat(const float* __restrict__ Cg,
                                              const float* __restrict__ SX,
                                              const short* __restrict__ W1g,
                                              const float* __restrict__ PB,
                                              float* __restrict__ ST){
  __shared__ float Cl[64][65];
  __shared__ float Wl[16][64];
  __shared__ float sxl[64];
  __shared__ float g2[2];
  int tid = threadIdx.x;
  int br = blockIdx.x >> 6, b = (blockIdx.x >> 4) & 3, g = blockIdx.x & 15;
  const float* Cb = Cg + b*4096;
  for(int u = tid; u < 4096; u += 256) Cl[u >> 6][u & 63] = Cb[u];
  const short* W1 = W1g + br*16384;
  for(int u = tid; u < 1024; u += 256){
    int nl = u >> 6, k = u & 63;
    int n = g*16 + nl;
    int fid = ((n >> 6)*4 + ((n >> 4) & 3))*2 + (k >> 5);
    int lane = ((k >> 3) & 3)*16 + (n & 15);
    Wl[nl][k] = s2f(W1[fid*512 + lane*8 + (k & 7)]);
  }
  if(tid < 64) sxl[tid] = SX[b*64 + tid];
  if(tid < 2) g2[tid] = 0.f;
  __syncthreads();
  int nl = tid >> 4, ic = tid & 15;
  float qa = 0.f, sa = 0.f;
  for(int io = 0; io < 4; io++){
    int i = ic*4 + io;
    float wi = Wl[nl][i];
    float dot = 0.f;
    #pragma unroll 8
    for(int j = 0; j < 64; j++) dot += Cl[i][j]*Wl[nl][j];
    qa += wi*dot;
    sa += wi*sxl[i];
  }
  for(int off = 8; off; off >>= 1){
    qa += __shfl_xor(qa, off);
    sa += __shfl_xor(sa, off);
  }
  if(ic == 0){
    float bn = PB[br*2048 + g*16 + nl];
    float hs = sa + 16384.f*bn;
    float hq = qa + 2.f*bn*sa + 16384.f*bn*bn;
    atomicAdd(&g2[0], hs); atomicAdd(&g2[1], hq);
  }
  __syncthreads();
  if(tid == 0){
    float* S1 = ST + br*192;
    S1[(b*16 + g)*2]     = g2[0];
    S1[(b*16 + g)*2 + 1] = g2[1];
  }
}

// ------- FF main: GEMM1+GN1+relu+GEMM2 -> h2 fp32 + per-channel sums ---------
__global__ __launch_bounds__(256, 2) void k_ffmain(const bf16* __restrict__ XO,
                                                   const short* __restrict__ W1g,
                                                   const short* __restrict__ W2g,
                                                   const float* __restrict__ PB,
                                                   const float* __restrict__ ST,
                                                   const float* __restrict__ z,
                                                   float* __restrict__ CS,
                                                   float* __restrict__ out){
  __shared__ short Ws1[16384];     // 32KB frag-order W1
  __shared__ short Ws2[16384];     // 32KB frag-order W2
  __shared__ short Hn[64][72];     // per-wave-private row slices
  __shared__ float mu1[16], rs1[16];
  __shared__ float cs[5][64];      // per-channel partial sums
  int tid = threadIdx.x;
  int br = blockIdx.x >> 8, rb = blockIdx.x & 255;
  int r0 = rb << 8, b = rb >> 6;
  const float* pb = PB + br*2048;
  {
    const uint4* g1 = (const uint4*)(W1g + br*16384);
    const uint4* g2w = (const uint4*)(W2g + br*16384);
    uint4* s1 = (uint4*)Ws1; uint4* s2 = (uint4*)Ws2;
    #pragma unroll
    for(int u = 0; u < 8; u++){
      s1[u*256 + tid] = g1[u*256 + tid];
      s2[u*256 + tid] = g2w[u*256 + tid];
    }
  }
  if(tid < 16){
    const float cnt = 262144.f;  // 128*128*16
    const float* S1 = ST + br*192;
    float s = S1[(b*16 + tid)*2], q = S1[(b*16 + tid)*2 + 1];
    float mean = s/cnt, var = q/cnt - mean*mean;
    mu1[tid] = mean; rs1[tid] = rsqrtf(fmaxf(var, 0.f) + EPSV);
  }
  {
    float* c1 = &cs[0][0];
    c1[tid] = 0.f;
    if(tid < 64) c1[256 + tid] = 0.f;
  }
  __syncthreads();
  int lane = tid & 63, w = tid >> 6, l15 = lane & 15, quad = lane >> 4;
  int myrow = w*16 + l15;
  float sh[4]  = {0,0,0,0}, sh2[4] = {0,0,0,0};
  float sz[4]  = {0,0,0,0}, sz2[4] = {0,0,0,0}, shz[4] = {0,0,0,0};
  for(int c = 0; c < 4; c++){
    const short* xop = (const short*)XO + ((size_t)(r0 + c*64 + myrow))*64;
    short8 a0 = *(const short8*)(xop + quad*8);
    short8 a1 = *(const short8*)(xop + 32 + quad*8);
    f32x4 acc2[4];
    #pragma unroll
    for(int t = 0; t < 4; t++) acc2[t] = (f32x4){0.f,0.f,0.f,0.f};
    for(int ch = 0; ch < 4; ch++){
      #pragma unroll
      for(int t = 0; t < 4; t++){
        int fid = (ch*4 + t)*2;
        short8 b0 = *(const short8*)(Ws1 + fid*512 + lane*8);
        short8 b1 = *(const short8*)(Ws1 + fid*512 + 512 + lane*8);
        f32x4 acc = {0.f,0.f,0.f,0.f};
        acc = __builtin_amdgcn_mfma_f32_16x16x32_bf16(a0, b0, acc, 0, 0, 0);
        acc = __builtin_amdgcn_mfma_f32_16x16x32_bf16(a1, b1, acc, 0, 0, 0);
        int n = ch*64 + t*16 + l15, gi = n >> 4;
        float w1v = pb[256 + n];
        float gwv = w1v * rs1[gi];
        float gbv = (pb[n] - mu1[gi])*rs1[gi]*w1v + pb[512 + n];
        #pragma unroll
        for(int r = 0; r < 4; r++){
          float hv = acc[r]*gwv + gbv;
          hv = hv > 0.f ? hv : 0.f;
          Hn[w*16 + quad*4 + r][t*16 + l15] = f2bs(hv);
        }
      }
      short8 ha0 = *(short8*)&Hn[myrow][quad*8];
      short8 ha1 = *(short8*)&Hn[myrow][32 + quad*8];
      #pragma unroll
      for(int t = 0; t < 4; t++){
        int fid = (ch*4 + t)*2;
        short8 b0 = *(const short8*)(Ws2 + fid*512 + lane*8);
        short8 b1 = *(const short8*)(Ws2 + fid*512 + 512 + lane*8);
        acc2[t] = __builtin_amdgcn_mfma_f32_16x16x32_bf16(ha0, b0, acc2[t], 0, 0, 0);
        acc2[t] = __builtin_amdgcn_mfma_f32_16x16x32_bf16(ha1, b1, acc2[t], 0, 0, 0);
      }
    }
    size_t obase_off = ((size_t)(b*2 + br)*16384 + (r0 & 16383) + c*64)*64;
    float* obase = out + obase_off;
    const float* zbase = z + obase_off;
    #pragma unroll
    for(int t = 0; t < 4; t++){
      int col = t*16 + l15;
      float bias2 = pb[768 + col];
      #pragma unroll
      for(int r = 0; r < 4; r++){
        size_t off = (size_t)(w*16 + quad*4 + r)*64 + col;
        float h2 = acc2[t][r] + bias2;
        float zv = zbase[off];
        obase[off] = h2;
        sh[t] += h2; sh2[t] += h2*h2;
        sz[t] += zv; sz2[t] += zv*zv; shz[t] += h2*zv;
      }
    }
  }
  #pragma unroll
  for(int t = 0; t < 4; t++){
    float v0 = sh[t], v1 = sh2[t], v2 = sz[t], v3 = sz2[t], v4 = shz[t];
    v0 += __shfl_xor(v0, 16); v0 += __shfl_xor(v0, 32);
    v1 += __shfl_xor(v1, 16); v1 += __shfl_xor(v1, 32);
    v2 += __shfl_xor(v2, 16); v2 += __shfl_xor(v2, 32);
    v3 += __shfl_xor(v3, 16); v3 += __shfl_xor(v3, 32);
    v4 += __shfl_xor(v4, 16); v4 += __shfl_xor(v4, 32);
    if(quad == 0){
      int ch = t*16 + l15;
      atomicAdd(&cs[0][ch], v0); atomicAdd(&cs[1][ch], v1);
      atomicAdd(&cs[2][ch], v2); atomicAdd(&cs[3][ch], v3);
      atomicAdd(&cs[4][ch], v4);
    }
  }
  __syncthreads();
  float* slab = CS + (size_t)blockIdx.x*320;
  const float* c1 = &cs[0][0];
  slab[tid] = c1[tid];
  if(tid < 64) slab[256 + tid] = c1[256 + tid];
}

// ------- StatB: GN2 params + analytic GN3 stats -> fused affine coeffs -------
__global__ __launch_bounds__(256) void k_statB(const float* __restrict__ CS,
                                               const float* __restrict__ PB,
                                               float* __restrict__ CF){
  __shared__ float chs[5][64];
  __shared__ float mu2s[4], rs2s[4], tg[4], tq[4], mu3s[4], rs3s[4];
  int br = blockIdx.x >> 2, b = blockIdx.x & 3;
  int tid = threadIdx.x;
  const float* base = CS + ((size_t)(br*256 + b*64))*320;
  float* c1 = &chs[0][0];
  for(int v = tid; v < 320; v += 256){
    float s = 0.f;
    for(int k = 0; k < 64; k++) s += base[(size_t)k*320 + v];
    c1[v] = s;
  }
  __syncthreads();
  if(tid < 4){
    float s = 0.f, q = 0.f;
    for(int o = tid*16; o < tid*16 + 16; o++){ s += chs[0][o]; q += chs[1][o]; }
    float mean = s/262144.f, var = q/262144.f - mean*mean;
    mu2s[tid] = mean; rs2s[tid] = rsqrtf(fmaxf(var, 0.f) + EPSV);
    tg[tid] = 0.f; tq[tid] = 0.f;
  }
  __syncthreads();
  const float* pb = PB + br*2048;
  if(tid < 64){
    int o = tid, g = o >> 4;
    float w2v = pb[832 + o], b2v = pb[896 + o];
    float gw = w2v*rs2s[g], gb = b2v - mu2s[g]*rs2s[g]*w2v;
    float Sh = chs[0][o], Sh2 = chs[1][o], Sz = chs[2][o], Sz2 = chs[3][o], Shz = chs[4][o];
    float st = gw*Sh + Sz + 16384.f*gb;
    float sq = gw*gw*Sh2 + Sz2 + 16384.f*gb*gb + 2.f*gw*Shz + 2.f*gw*gb*Sh + 2.f*gb*Sz;
    atomicAdd(&tg[g], st); atomicAdd(&tq[g], sq);
  }
  __syncthreads();
  if(tid < 4){
    float mean = tg[tid]/262144.f, var = tq[tid]/262144.f - mean*mean;
    mu3s[tid] = mean; rs3s[tid] = rsqrtf(fmaxf(var, 0.f) + EPSV);
  }
  __syncthreads();
  if(tid < 64){
    int o = tid, g = o >> 4;
    float w2v = pb[832 + o], b2v = pb[896 + o];
    float gw = w2v*rs2s[g], gb = b2v - mu2s[g]*rs2s[g]*w2v;
    float w3v = pb[960 + o], b3v = pb[1024 + o];
    float gw3 = w3v*rs3s[g], gb3 = b3v - mu3s[g]*rs3s[g]*w3v;
    float* cf = CF + (size_t)(br*4 + b)*192;
    cf[o]       = gw*gw3;          // alpha (h2 coefficient)
    cf[64 + o]  = gw3;             // beta  (z coefficient)
    cf[128 + o] = gb*gw3 + gb3;    // gamma
  }
}

// ------- Final: out = alpha*h2 + beta*z + gamma, float4, in place ------------
__global__ __launch_bounds__(256) void k_final(const float* __restrict__ z,
                                               const float* __restrict__ CF,
                                               float* __restrict__ out){
  int tid = blockIdx.x*256 + threadIdx.x;
  const float4* z4 = (const float4*)z;
  const float4* cf4 = (const float4*)CF;
  float4* o4 = (float4*)out;
  #pragma unroll
  for(int r = 0; r < 8; r++){
    int i4 = r*262144 + tid;
    int s = i4 >> 18;                 // (b*2+br)
    int b = s >> 1, br = s & 1;
    int cbase = (br*4 + b)*48 + (i4 & 15);
    float4 a = cf4[cbase], bb = cf4[cbase + 16], g = cf4[cbase + 32];
    float4 h = o4[i4], zv = z4[i4];
    o4[i4] = make_float4(h.x*a.x + zv.x*bb.x + g.x,
                         h.y*a.y + zv.y*bb.y + g.y,
                         h.z*a.z + zv.z*bb.z + g.z,
                         h.w*a.w + zv.w*bb.w + g.w);
  }
}

extern "C" void kernel_launch(void* const* d_in, const int* in_sizes, int n_in,
                              void* d_out, int out_size, void* d_ws, size_t ws_size,
                              hipStream_t stream){
  const float* z   = (const float*)d_in[0];
  const float* x   = (const float*)d_in[1];
  const float* fw1 = (const float*)d_in[2];
  const float* fw2 = (const float*)d_in[3];
  char* ws = (char*)d_ws;
  // workspace layout (byte offsets)
  float2* Y   = (float2*)(ws + 0);           // 4,194,304 B
  float2* X2  = (float2*)(ws + 4194304);     // 1,048,576 B
  float2* T   = Y;                           // alias: Y dead after k_xdft
  bf16*   XO  = (bf16*)(ws + 5242880);       // 8,388,608 B
  float*  ST  = (float*)(ws + 13631488);     // 2,048 B
  short*  W1g = (short*)(ws + 13633536);     // 65,536 B
  short*  W2g = (short*)(ws + 13699072);     // 65,536 B
  float2* TWY = (float2*)(ws + 13764608);    // 16,384 B
  float2* TWX = (float2*)(ws + 13780992);    // 32,768 B
  float*  PB  = (float*)(ws + 13813760);     // 16,384 B
  float2* FWT = (float2*)(ws + 13830144);    // 16,777,216 B -> ends 30,607,360
  // Aliases into the FWT region (FWT dead after k_mix):
  float*  Cg  = (float*)(ws + 13830144);     // 65,536 B  (4 x 64 x 64), zeroed in k_inv2
  float*  SX  = Cg + 16384;                  // 1,024 B   (4 x 64), zeroed in k_inv2
  float*  CS  = (float*)(ws + 14878720);     // 655,360 B (512 slabs x 320)
  float*  CF  = (float*)(ws + 15927296);     // 6,144 B   (8 x 192)

  const float* p[20];
  for(int i = 0; i < 20; i++) p[i] = (const float*)d_in[4 + i];

  k_prep<<<802, 256, 0, stream>>>(fw1, fw2, FWT,
                                  p[0],p[1],p[2],p[3],p[4],p[5],p[6],p[7],p[8],p[9],
                                  p[10],p[11],p[12],p[13],p[14],p[15],p[16],p[17],p[18],p[19],
                                  W1g, W2g, TWY, TWX, PB, ST);
  k_ydft<<<512, 256, 0, stream>>>(x, z, TWY, Y);
  k_xdft<<<256, 256, 0, stream>>>(Y, TWX, X2);
  k_mix<<<256, 256, 0, stream>>>(X2, FWT);
  k_inv1<<<256, 256, 0, stream>>>(X2, TWX, T);
  k_inv2<<<256, 256, 0, stream>>>(T, TWY, XO, Cg);
  k_cov<<<64, 256, 0, stream>>>(XO, Cg, SX);
  k_stat<<<128, 256, 0, stream>>>(Cg, SX, W1g, PB, ST);
  k_ffmain<<<512, 256, 0, stream>>>(XO, W1g, W2g, PB, ST, z, CS, (float*)d_out);
  k_statB<<<8, 256, 0, stream>>>(CS, PB, CF);
  k_final<<<1024, 256, 0, stream>>>(z, CF, (float*)d_out);
}

// Round 5
// 247.344 us; speedup vs baseline: 1.6724x; 1.0581x over previous
//
#include <hip/hip_runtime.h>
#include <hip/hip_bf16.h>

typedef __hip_bfloat16 bf16;
typedef __attribute__((ext_vector_type(8))) short short8;   // 8 bf16 (4 VGPRs)
typedef __attribute__((ext_vector_type(4))) float f32x4;    // 4 fp32 acc

#define PI2 6.283185307179586f
#define EPSV 1e-5f

__device__ __forceinline__ short f2bs(float f){
  bf16 h = __float2bfloat16(f);
  short s; __builtin_memcpy(&s, &h, 2); return s;
}
__device__ __forceinline__ float s2f(short s){
  bf16 h; __builtin_memcpy(&h, &s, 2); return __bfloat162float(h);
}
__device__ __forceinline__ float4 f4add(float4 a, float4 b){ return make_float4(a.x+b.x, a.y+b.y, a.z+b.z, a.w+b.w); }
__device__ __forceinline__ float4 f4sub(float4 a, float4 b){ return make_float4(a.x-b.x, a.y-b.y, a.z-b.z, a.w-b.w); }

// ------ Prep+ydft merged: blocks [0,512) ydft | [512,1024) FWT | rest misc ---
// ydft computes its own twiddles (no TWY dependency -> blocks independent).
// sm sizing: ydft = 16K(PQ) + 16K(RS) + 4K(twl float4[8][32]) = 36864 B.
// (Round-4 bug: twl was float4[16][32]=8K placed at 32768 in a 34816-B buffer
//  -> rows 4..15 out of bounds -> ky 8..15 garbage. Now only the 8 used rows.)
__global__ __launch_bounds__(256) void k_prep_ydft(
    const float* __restrict__ x, const float* __restrict__ z,
    const float* __restrict__ fw1, const float* __restrict__ fw2,
    float2* __restrict__ FWT,
    const float* __restrict__ b_l1w, const float* __restrict__ b_l1b,
    const float* __restrict__ b_l2w, const float* __restrict__ b_l2b,
    const float* __restrict__ b_g1w, const float* __restrict__ b_g1b,
    const float* __restrict__ b_g2w, const float* __restrict__ b_g2b,
    const float* __restrict__ b_g3w, const float* __restrict__ b_g3b,
    const float* __restrict__ f_l1w, const float* __restrict__ f_l1b,
    const float* __restrict__ f_l2w, const float* __restrict__ f_l2b,
    const float* __restrict__ f_g1w, const float* __restrict__ f_g1b,
    const float* __restrict__ f_g2w, const float* __restrict__ f_g2b,
    const float* __restrict__ f_g3w, const float* __restrict__ f_g3b,
    short* __restrict__ W1g, short* __restrict__ W2g,
    float2* __restrict__ TWY, float2* __restrict__ TWX,
    float* __restrict__ PB, float* __restrict__ ST,
    float2* __restrict__ Y){
  __shared__ __align__(16) char sm[36864];
  int tid = threadIdx.x;
  int bi = blockIdx.x;
  if(bi < 512){
    // ---- ydft: radix-4 over n; PQ/RS packed; on-the-fly twiddles ----
    float2 (*PQ)[64] = (float2(*)[64])sm;              // 16KB
    float2 (*RS)[64] = (float2(*)[64])(sm + 16384);    // 16KB
    float4 (*twl)[32] = (float4(*)[32])(sm + 32768);   // 4KB [kq2][np], kq2<8
    int b = bi >> 7, m = bi & 127;
    const float4* xp = (const float4*)(x + ((size_t)(b*128 + m)*128)*64);
    const float4* zp = (const float4*)(z + ((size_t)((b*2 + 0)*128 + m)*128)*64);
    int i4 = tid & 15, n0 = tid >> 4;
    #pragma unroll
    for(int it = 0; it < 2; it++){
      int np = n0 + it*16;
      float4 ea = f4sub(xp[np*16 + i4],      zp[np*16 + i4]);
      float4 eb = f4sub(xp[(np+32)*16 + i4], zp[(np+32)*16 + i4]);
      float4 ec = f4sub(xp[(np+64)*16 + i4], zp[(np+64)*16 + i4]);
      float4 ed = f4sub(xp[(np+96)*16 + i4], zp[(np+96)*16 + i4]);
      float4 sac = f4add(ea, ec), sbd = f4add(eb, ed);
      float4 P = f4add(sac, sbd), Q = f4sub(sac, sbd);
      float4 R = f4sub(ea, ec),  S = f4sub(eb, ed);
      *(float4*)&PQ[np][i4*4]     = make_float4(P.x, Q.x, P.y, Q.y);
      *(float4*)&PQ[np][i4*4 + 2] = make_float4(P.z, Q.z, P.w, Q.w);
      *(float4*)&RS[np][i4*4]     = make_float4(R.x, S.x, R.y, S.y);
      *(float4*)&RS[np][i4*4 + 2] = make_float4(R.z, S.z, R.w, S.w);
    }
    {
      // 256 threads cover exactly the 8 used rows x 32 np.
      int kq2 = tid >> 5, np = tid & 31;          // kq2 in [0,8)
      int ky0 = (kq2 >> 1)*4 + (kq2 & 1)*2;       // rows 2k->ky0=4k, 2k+1->4k+2
      float s0, c0, s1, c1;
      sincosf(PI2*(float)((ky0*np) & 127)/128.f, &s0, &c0);
      sincosf(PI2*(float)(((ky0+1)*np) & 127)/128.f, &s1, &c1);
      twl[kq2][np] = make_float4(c0, s0, c1, s1);
    }
    __syncthreads();
    int i = tid & 63, kq = tid >> 6;
    float re[4] = {0,0,0,0}, im[4] = {0,0,0,0};
    for(int np = 0; np < 32; np++){
      float2 pq = PQ[np][i];
      float2 rs = RS[np][i];
      float4 t01 = twl[kq*2][np];       // (c,s) for ky=kq*4, kq*4+1
      float4 t23 = twl[kq*2 + 1][np];   // (c,s) for ky=kq*4+2, kq*4+3
      re[0] += pq.x*t01.x;               im[0] -= pq.x*t01.y;
      re[1] += rs.x*t01.z - rs.y*t01.w;  im[1] -= rs.y*t01.z + rs.x*t01.w;
      re[2] += pq.y*t23.x;               im[2] -= pq.y*t23.y;
      re[3] += rs.x*t23.z + rs.y*t23.w;  im[3] += rs.y*t23.z - rs.x*t23.w;
    }
    #pragma unroll
    for(int j = 0; j < 4; j++)
      Y[((b*128 + m)*16 + kq*4 + j)*64 + i] = make_float2(re[j], im[j]);
    return;
  }
  if(bi < 1024){
    // ---- FWT transpose ----
    float (*Ls)[512] = (float(*)[512])sm;   // 32KB
    int bb = bi - 512;
    int arr = bb >> 8, rem = bb & 255;
    int i = rem >> 2, o0 = (rem & 3) * 16;
    const float* src = (arr ? fw2 : fw1) + ((size_t)(i*64 + o0))*512;
    for(int idx = tid; idx < 8192; idx += 256)
      Ls[idx >> 9][idx & 511] = src[idx];
    __syncthreads();
    int kxw = tid >> 4, ky = tid & 15;
    float2* dst = FWT + ((size_t)((arr*16 + kxw)*16 + ky))*4096 + i*64 + o0;
    for(int ol = 0; ol < 16; ol++)
      dst[ol] = make_float2(Ls[ol][tid*2], Ls[ol][tid*2 + 1]);
    return;
  }
  int i = (bi - 1024)*256 + tid;
  if(i < 32768){                         // W1g fragment layout
    int br = i >> 14, r = i & 16383;
    int fid = r >> 9, lane = (r >> 3) & 63, e = r & 7;
    int hb = fid & 1, t = (fid >> 1) & 3, ch = fid >> 3;
    int l15 = lane & 15, quad = lane >> 4;
    int n = ch*64 + t*16 + l15;
    int k = hb*32 + quad*8 + e;
    const float* src = br ? f_l1w : b_l1w;
    W1g[i] = f2bs(src[k*256 + n]);
    return;
  }
  i -= 32768;
  if(i < 32768){                         // W2g fragment layout
    int br = i >> 14, r = i & 16383;
    int fid = r >> 9, lane = (r >> 3) & 63, e = r & 7;
    int hb = fid & 1, t = (fid >> 1) & 3, ch = fid >> 3;
    int l15 = lane & 15, quad = lane >> 4;
    int n = t*16 + l15;
    int k = ch*64 + hb*32 + quad*8 + e;
    const float* src = br ? f_l2w : b_l2w;
    W2g[i] = f2bs(src[k*64 + n]);
    return;
  }
  i -= 32768;
  if(i < 2048){                          // TWY[ky][n]
    int ky = i >> 7, n = i & 127;
    float ang = PI2 * (float)((ky*n) & 127) / 128.0f;
    float s, c; sincosf(ang, &s, &c);
    TWY[i] = make_float2(c, s);
    return;
  }
  i -= 2048;
  if(i < 4096){                          // TWX[kp][m]
    int kp = i >> 7, m = i & 127;
    int kx = kp < 16 ? kp : 96 + kp;
    float ang = PI2 * (float)((kx*m) & 127) / 128.0f;
    float s, c; sincosf(ang, &s, &c);
    TWX[i] = make_float2(c, s);
    return;
  }
  i -= 4096;
  if(i < 384){ ST[i] = 0.f; return; }    // zero stats
  i -= 384;
  if(i < 2176){                          // param block
    int br = i >= 1088; int o = i - br*1088;
    float* pb = PB + br*2048;
    float v;
    if(o < 256)       v = (br ? f_l1b : b_l1b)[o];
    else if(o < 512)  v = (br ? f_g1w : b_g1w)[o-256];
    else if(o < 768)  v = (br ? f_g1b : b_g1b)[o-512];
    else if(o < 832)  v = (br ? f_l2b : b_l2b)[o-768];
    else if(o < 896)  v = (br ? f_g2w : b_g2w)[o-832];
    else if(o < 960)  v = (br ? f_g2b : b_g2b)[o-896];
    else if(o < 1024) v = (br ? f_g3w : b_g3w)[o-960];
    else              v = (br ? f_g3b : b_g3b)[o-1024];
    pb[o] = v;
  }
}

// ------- Stage 2: DFT over x, radix-2 over m, 4-way m-split, 512 thr --------
__global__ __launch_bounds__(512) void k_xdft(const float2* __restrict__ Y,
                                              const float2* __restrict__ TWX,
                                              float2* __restrict__ X2){
  __shared__ float2 twl[16][64];
  __shared__ float sc[3][128][8];
  int bi = blockIdx.x;
  int b = bi >> 6, ky = (bi >> 2) & 15, half = (bi >> 1) & 1, ih = bi & 1;
  int tid = threadIdx.x;
  for(int idx = tid; idx < 1024; idx += 512)
    twl[idx >> 6][idx & 63] = TWX[(half*16 + (idx >> 6))*128 + (idx & 63)];
  __syncthreads();
  int i = ih*32 + (tid & 31), grp = (tid >> 5) & 3, mq = tid >> 7;
  const float2* yb = Y + (size_t)b*131072 + ky*64 + i;
  float re[4] = {0,0,0,0}, im[4] = {0,0,0,0};
  for(int mi = 0; mi < 16; mi++){
    int mp = mq*16 + mi;
    float2 y1 = yb[(size_t)mp*1024];
    float2 y2 = yb[(size_t)(mp + 64)*1024];
    float2 ye = make_float2(y1.x + y2.x, y1.y + y2.y);
    float2 yo = make_float2(y1.x - y2.x, y1.y - y2.y);
    float2 t0 = twl[grp*4 + 0][mp];
    float2 t1 = twl[grp*4 + 1][mp];
    float2 t2 = twl[grp*4 + 2][mp];
    float2 t3 = twl[grp*4 + 3][mp];
    re[0] += ye.x*t0.x + ye.y*t0.y;  im[0] += ye.y*t0.x - ye.x*t0.y;
    re[1] += yo.x*t1.x + yo.y*t1.y;  im[1] += yo.y*t1.x - yo.x*t1.y;
    re[2] += ye.x*t2.x + ye.y*t2.y;  im[2] += ye.y*t2.x - ye.x*t2.y;
    re[3] += yo.x*t3.x + yo.y*t3.y;  im[3] += yo.y*t3.x - yo.x*t3.y;
  }
  if(mq){
    int sl = tid & 127;
    #pragma unroll
    for(int j = 0; j < 4; j++){ sc[mq-1][sl][j] = re[j]; sc[mq-1][sl][4 + j] = im[j]; }
  }
  __syncthreads();
  if(!mq){
    const float scn = 1.0f/128.0f;   // forward ortho norm (both axes)
    #pragma unroll
    for(int j = 0; j < 4; j++){
      float rr = (re[j] + sc[0][tid][j] + sc[1][tid][j] + sc[2][tid][j])*scn;
      float ii = (im[j] + sc[0][tid][4+j] + sc[1][tid][4+j] + sc[2][tid][4+j])*scn;
      int kp = half*16 + grp*4 + j;
      X2[((b*32 + kp)*16 + ky)*64 + i] = make_float2(rr, ii);
    }
  }
}

// ------- Stage 3: per-mode 64x64 complex mix, 2 p/block, 4-way i-split ------
__global__ __launch_bounds__(512) void k_mix(float2* __restrict__ X2,
                                             const float2* __restrict__ FWT){
  __shared__ float2 Xs[2][4][64];   // [pair_local][batch][i]
  __shared__ float sc[3][2][64][8];
  int tid = threadIdx.x;
  {
    int pl = tid >> 8, bq = (tid >> 6) & 3, ii = tid & 63;
    int p = blockIdx.x*2 + pl; int kp = p >> 4, kyy = p & 15;
    Xs[pl][bq][ii] = X2[((bq*32 + kp)*16 + kyy)*64 + ii];
  }
  __syncthreads();
  int o = tid & 63, w = tid >> 6, pl = w >> 2, iq = w & 3;
  int p = blockIdx.x*2 + pl; int kp = p >> 4, ky = p & 15;
  int arr = kp < 16 ? 0 : 1, kxw = kp < 16 ? kp : kp - 16;
  const float2* wp = FWT + ((size_t)((arr*16 + kxw)*16 + ky))*4096;
  float rr[4] = {0,0,0,0}, ii[4] = {0,0,0,0};
  for(int i = iq*16; i < iq*16 + 16; i++){
    float2 wv = wp[i*64 + o];
    #pragma unroll
    for(int b = 0; b < 4; b++){
      float xr = Xs[pl][b][i].x, xi = Xs[pl][b][i].y;
      rr[b] += xr*wv.x - xi*wv.y;
      ii[b] += xr*wv.y + xi*wv.x;
    }
  }
  if(iq){
    #pragma unroll
    for(int b = 0; b < 4; b++){ sc[iq-1][pl][o][b*2] = rr[b]; sc[iq-1][pl][o][b*2 + 1] = ii[b]; }
  }
  __syncthreads();
  if(!iq){
    #pragma unroll
    for(int b = 0; b < 4; b++){
      float r2 = rr[b] + sc[0][pl][o][b*2] + sc[1][pl][o][b*2] + sc[2][pl][o][b*2];
      float i2 = ii[b] + sc[0][pl][o][b*2+1] + sc[1][pl][o][b*2+1] + sc[2][pl][o][b*2+1];
      X2[((b*32 + kp)*16 + ky)*64 + o] = make_float2(r2, i2);
    }
  }
}

// ------- Stage 4: inverse DFT over kx, radix-2 m, 2-way kp-split, 512 thr ---
__global__ __launch_bounds__(512) void k_inv1(const float2* __restrict__ OF,
                                              const float2* __restrict__ TWX,
                                              float2* __restrict__ T){
  __shared__ float2 Fl[32][16];
  __shared__ float2 twl[32][64];
  __shared__ float sc[256][16];
  int bi = blockIdx.x;
  int b = bi >> 6, ky = (bi >> 2) & 15, oq = bi & 3;
  int tid = threadIdx.x;
  {
    int kp = tid >> 4, ol = tid & 15;
    Fl[kp][ol] = OF[((b*32 + kp)*16 + ky)*64 + oq*16 + ol];
  }
  for(int idx = tid; idx < 2048; idx += 512){
    int kp = idx >> 6, ml = idx & 63;
    twl[kp][ml] = TWX[kp*128 + ml];
  }
  __syncthreads();
  int ol = tid & 15, mg = (tid >> 4) & 15, kh = tid >> 8;
  float reE[4] = {0,0,0,0}, imE[4] = {0,0,0,0};
  float reO[4] = {0,0,0,0}, imO[4] = {0,0,0,0};
  for(int ip = 0; ip < 8; ip++){
    int kp = kh*16 + ip*2;
    float2 fe = Fl[kp][ol], fo = Fl[kp + 1][ol];
    #pragma unroll
    for(int u = 0; u < 4; u++){
      float2 te = twl[kp][mg*4 + u], to = twl[kp + 1][mg*4 + u];
      reE[u] += fe.x*te.x - fe.y*te.y;
      imE[u] += fe.x*te.y + fe.y*te.x;
      reO[u] += fo.x*to.x - fo.y*to.y;
      imO[u] += fo.x*to.y + fo.y*to.x;
    }
  }
  if(kh){
    int sl = tid & 255;
    #pragma unroll
    for(int u = 0; u < 4; u++){
      sc[sl][u] = reE[u]; sc[sl][4 + u] = imE[u];
      sc[sl][8 + u] = reO[u]; sc[sl][12 + u] = imO[u];
    }
  }
  __syncthreads();
  if(!kh){
    int o = oq*16 + ol;
    #pragma unroll
    for(int u = 0; u < 4; u++){
      float rE = reE[u] + sc[tid][u],     iE = imE[u] + sc[tid][4 + u];
      float rO = reO[u] + sc[tid][8 + u], iO = imO[u] + sc[tid][12 + u];
      int ml = mg*4 + u;
      T[((b*128 + ml)*16 + ky)*64 + o]      = make_float2(rE + rO, iE + iO);
      T[((b*128 + ml + 64)*16 + ky)*64 + o] = make_float2(rE - rO, iE - iO);
    }
  }
}

// ---------- Stage 5: hermitian C2R over ky, radix-2 over n, 512 blocks ------
__global__ __launch_bounds__(256) void k_inv2(const float2* __restrict__ T,
                                              const float2* __restrict__ TWY,
                                              bf16* __restrict__ XO,
                                              float* __restrict__ CZ){
  __shared__ float2 twl[16][64];
  int bi = blockIdx.x;
  int b = bi >> 7, m = bi & 127;
  int tid = threadIdx.x;
  int flat = bi*256 + tid;
  if(flat < 16640) CZ[flat] = 0.f;      // zero Cg (16384) + SX (256)
  for(int idx = tid; idx < 1024; idx += 256)
    twl[idx >> 6][idx & 63] = TWY[(idx >> 6)*128 + (idx & 63)];
  int o = tid & 63, ng = tid >> 6;
  const float2* tp = T + ((size_t)(b*128 + m)*16)*64 + o;
  float t0a = tp[0].x;
  float ax[15], ay[15];
  #pragma unroll
  for(int u = 0; u < 15; u++){
    float2 v = tp[(u + 1)*64];
    ax[u] = 2.f*v.x; ay[u] = 2.f*v.y;
  }
  __syncthreads();
  const float scn = 1.0f/128.0f;   // inverse ortho norm (both axes)
  bf16* xo = XO + ((size_t)(b*128 + m)*128)*64 + o;
  for(int np = ng*16; np < ng*16 + 16; np++){
    float A = t0a, B = 0.f;
    #pragma unroll
    for(int u = 0; u < 15; u++){   // ky = u+1; even ky <=> odd u
      float2 t = twl[u + 1][np];
      float pr = ax[u]*t.x - ay[u]*t.y;
      if(u & 1) A += pr; else B += pr;
    }
    xo[(size_t)np*64]        = __float2bfloat16((A + B)*scn);
    xo[(size_t)(np + 64)*64] = __float2bfloat16((A - B)*scn);
  }
}

// ------- Cov: S = X^T X (64x64) and sx = colsum(X) per b, via MFMA ----------
// grid 128: b = bi>>5, chunk = bi&31 (2 sub-tiles of 256 positions).
__global__ __launch_bounds__(256) void k_cov(const bf16* __restrict__ XO,
                                             float* __restrict__ Cg,
                                             float* __restrict__ SX){
  __shared__ short XT[64][264];    // [ch][pos], padded row
  __shared__ float sxl[64];
  int tid = threadIdx.x;
  int b = blockIdx.x >> 5, ck = blockIdx.x & 31;
  if(tid < 64) sxl[tid] = 0.f;
  float sxp[8];
  #pragma unroll
  for(int e = 0; e < 8; e++) sxp[e] = 0.f;
  int c0 = (tid & 7)*8;
  int lane = tid & 63, w = tid >> 6, l15 = lane & 15, quad = lane >> 4;
  f32x4 acc[4];
  #pragma unroll
  for(int tj = 0; tj < 4; tj++) acc[tj] = (f32x4){0.f,0.f,0.f,0.f};
  for(int st = 0; st < 2; st++){
    size_t pbase = (size_t)b*16384 + (size_t)ck*512 + st*256;
    const short* xg = (const short*)XO + pbase*64;
    __syncthreads();
    for(int it = 0; it < 8; it++){
      int p = it*32 + (tid >> 3);
      short8 v = *(const short8*)(xg + (size_t)p*64 + c0);
      #pragma unroll
      for(int e = 0; e < 8; e++){
        XT[c0+e][p] = v[e];
        sxp[e] += s2f(v[e]);
      }
    }
    __syncthreads();
    for(int kk = 0; kk < 8; kk++){
      short8 a = *(const short8*)&XT[w*16 + l15][kk*32 + quad*8];
      #pragma unroll
      for(int tj = 0; tj < 4; tj++){
        short8 bfr = *(const short8*)&XT[tj*16 + l15][kk*32 + quad*8];
        acc[tj] = __builtin_amdgcn_mfma_f32_16x16x32_bf16(a, bfr, acc[tj], 0, 0, 0);
      }
    }
  }
  #pragma unroll
  for(int e = 0; e < 8; e++) atomicAdd(&sxl[c0+e], sxp[e]);
  __syncthreads();
  float* Cb = Cg + b*4096;
  #pragma unroll
  for(int tj = 0; tj < 4; tj++)
    #pragma unroll
    for(int r = 0; r < 4; r++)
      atomicAdd(&Cb[(w*16 + quad*4 + r)*64 + tj*16 + l15], acc[tj][r]);
  if(tid < 64) atomicAdd(&SX[b*64 + tid], sxl[tid]);
}

// ------- Stat: GN1 group sums from quadratic form; writes S1 directly -------
__global__ __launch_bounds__(256) void k_stat(const float* __restrict__ Cg,
                                              const float* __restrict__ SX,
                                              const short* __restrict__ W1g,
                                              const float* __restrict__ PB,
                                              float* __restrict__ ST){
  __shared__ float Cl[64][65];
  __shared__ float Wl[16][64];
  __shared__ float sxl[64];
  __shared__ float g2[2];
  int tid = threadIdx.x;
  int br = blockIdx.x >> 6, b = (blockIdx.x >> 4) & 3, g = blockIdx.x & 15;
  const float* Cb = Cg + b*4096;
  for(int u = tid; u < 4096; u += 256) Cl[u >> 6][u & 63] = Cb[u];
  const short* W1 = W1g + br*16384;
  for(int u = tid; u < 1024; u += 256){
    int nl = u >> 6, k = u & 63;
    int n = g*16 + nl;
    int fid = ((n >> 6)*4 + ((n >> 4) & 3))*2 + (k >> 5);
    int lane = ((k >> 3) & 3)*16 + (n & 15);
    Wl[nl][k] = s2f(W1[fid*512 + lane*8 + (k & 7)]);
  }
  if(tid < 64) sxl[tid] = SX[b*64 + tid];
  if(tid < 2) g2[tid] = 0.f;
  __syncthreads();
  int nl = tid >> 4, ic = tid & 15;
  float qa = 0.f, sa = 0.f;
  for(int io = 0; io < 4; io++){
    int i = ic*4 + io;
    float wi = Wl[nl][i];
    float dot = 0.f;
    #pragma unroll 8
    for(int j = 0; j < 64; j++) dot += Cl[i][j]*Wl[nl][j];
    qa += wi*dot;
    sa += wi*sxl[i];
  }
  for(int off = 8; off; off >>= 1){
    qa += __shfl_xor(qa, off);
    sa += __shfl_xor(sa, off);
  }
  if(ic == 0){
    float bn = PB[br*2048 + g*16 + nl];
    float hs = sa + 16384.f*bn;
    float hq = qa + 2.f*bn*sa + 16384.f*bn*bn;
    atomicAdd(&g2[0], hs); atomicAdd(&g2[1], hq);
  }
  __syncthreads();
  if(tid == 0){
    float* S1 = ST + br*192;
    S1[(b*16 + g)*2]     = g2[0];
    S1[(b*16 + g)*2 + 1] = g2[1];
  }
}

// ------- FF main: GEMM1+GN1+relu+GEMM2 -> h2 fp32 + per-channel sums --------
// A-frags for all 4 c-tiles prefetched; z prefetched per-c ahead of MFMAs.
__global__ __launch_bounds__(256, 2) void k_ffmain(const bf16* __restrict__ XO,
                                                   const short* __restrict__ W1g,
                                                   const short* __restrict__ W2g,
                                                   const float* __restrict__ PB,
                                                   const float* __restrict__ ST,
                                                   const float* __restrict__ z,
                                                   float* __restrict__ CS,
                                                   float* __restrict__ out){
  __shared__ short Ws1[16384];     // 32KB frag-order W1
  __shared__ short Ws2[16384];     // 32KB frag-order W2
  __shared__ short Hn[64][72];     // per-wave-private row slices
  __shared__ float mu1[16], rs1[16];
  __shared__ float cs[5][64];      // per-channel partial sums
  int tid = threadIdx.x;
  int br = blockIdx.x >> 8, rb = blockIdx.x & 255;
  int r0 = rb << 8, b = rb >> 6;
  const float* pb = PB + br*2048;
  int lane = tid & 63, w = tid >> 6, l15 = lane & 15, quad = lane >> 4;
  int myrow = w*16 + l15;
  short8 a0r[4], a1r[4];
  #pragma unroll
  for(int c = 0; c < 4; c++){
    const short* xop = (const short*)XO + ((size_t)(r0 + c*64 + myrow))*64;
    a0r[c] = *(const short8*)(xop + quad*8);
    a1r[c] = *(const short8*)(xop + 32 + quad*8);
  }
  {
    const uint4* g1 = (const uint4*)(W1g + br*16384);
    const uint4* g2w = (const uint4*)(W2g + br*16384);
    uint4* s1 = (uint4*)Ws1; uint4* s2 = (uint4*)Ws2;
    #pragma unroll
    for(int u = 0; u < 8; u++){
      s1[u*256 + tid] = g1[u*256 + tid];
      s2[u*256 + tid] = g2w[u*256 + tid];
    }
  }
  if(tid < 16){
    const float cnt = 262144.f;  // 128*128*16
    const float* S1 = ST + br*192;
    float s = S1[(b*16 + tid)*2], q = S1[(b*16 + tid)*2 + 1];
    float mean = s/cnt, var = q/cnt - mean*mean;
    mu1[tid] = mean; rs1[tid] = rsqrtf(fmaxf(var, 0.f) + EPSV);
  }
  {
    float* c1 = &cs[0][0];
    c1[tid] = 0.f;
    if(tid < 64) c1[256 + tid] = 0.f;
  }
  __syncthreads();
  float sh[4]  = {0,0,0,0}, sh2[4] = {0,0,0,0};
  float sz[4]  = {0,0,0,0}, sz2[4] = {0,0,0,0}, shz[4] = {0,0,0,0};
  #pragma unroll
  for(int c = 0; c < 4; c++){
    size_t obase_off = ((size_t)(b*2 + br)*16384 + (r0 & 16383) + c*64)*64;
    const float* zbase = z + obase_off;
    float zr[16];
    #pragma unroll
    for(int t = 0; t < 4; t++)
      #pragma unroll
      for(int r = 0; r < 4; r++)
        zr[t*4 + r] = zbase[(size_t)(w*16 + quad*4 + r)*64 + t*16 + l15];
    f32x4 acc2[4];
    #pragma unroll
    for(int t = 0; t < 4; t++) acc2[t] = (f32x4){0.f,0.f,0.f,0.f};
    for(int ch = 0; ch < 4; ch++){
      #pragma unroll
      for(int t = 0; t < 4; t++){
        int fid = (ch*4 + t)*2;
        short8 b0 = *(const short8*)(Ws1 + fid*512 + lane*8);
        short8 b1 = *(const short8*)(Ws1 + fid*512 + 512 + lane*8);
        f32x4 acc = {0.f,0.f,0.f,0.f};
        acc = __builtin_amdgcn_mfma_f32_16x16x32_bf16(a0r[c], b0, acc, 0, 0, 0);
        acc = __builtin_amdgcn_mfma_f32_16x16x32_bf16(a1r[c], b1, acc, 0, 0, 0);
        int n = ch*64 + t*16 + l15, gi = n >> 4;
        float w1v = pb[256 + n];
        float gwv = w1v * rs1[gi];
        float gbv = (pb[n] - mu1[gi])*rs1[gi]*w1v + pb[512 + n];
        #pragma unroll
        for(int r = 0; r < 4; r++){
          float hv = acc[r]*gwv + gbv;
          hv = hv > 0.f ? hv : 0.f;
          Hn[w*16 + quad*4 + r][t*16 + l15] = f2bs(hv);
        }
      }
      short8 ha0 = *(short8*)&Hn[myrow][quad*8];
      short8 ha1 = *(short8*)&Hn[myrow][32 + quad*8];
      #pragma unroll
      for(int t = 0; t < 4; t++){
        int fid = (ch*4 + t)*2;
        short8 b0 = *(const short8*)(Ws2 + fid*512 + lane*8);
        short8 b1 = *(const short8*)(Ws2 + fid*512 + 512 + lane*8);
        acc2[t] = __builtin_amdgcn_mfma_f32_16x16x32_bf16(ha0, b0, acc2[t], 0, 0, 0);
        acc2[t] = __builtin_amdgcn_mfma_f32_16x16x32_bf16(ha1, b1, acc2[t], 0, 0, 0);
      }
    }
    float* obase = out + obase_off;
    #pragma unroll
    for(int t = 0; t < 4; t++){
      int col = t*16 + l15;
      float bias2 = pb[768 + col];
      #pragma unroll
      for(int r = 0; r < 4; r++){
        size_t off = (size_t)(w*16 + quad*4 + r)*64 + col;
        float h2 = acc2[t][r] + bias2;
        float zv = zr[t*4 + r];
        obase[off] = h2;
        sh[t] += h2; sh2[t] += h2*h2;
        sz[t] += zv; sz2[t] += zv*zv; shz[t] += h2*zv;
      }
    }
  }
  #pragma unroll
  for(int t = 0; t < 4; t++){
    float v0 = sh[t], v1 = sh2[t], v2 = sz[t], v3 = sz2[t], v4 = shz[t];
    v0 += __shfl_xor(v0, 16); v0 += __shfl_xor(v0, 32);
    v1 += __shfl_xor(v1, 16); v1 += __shfl_xor(v1, 32);
    v2 += __shfl_xor(v2, 16); v2 += __shfl_xor(v2, 32);
    v3 += __shfl_xor(v3, 16); v3 += __shfl_xor(v3, 32);
    v4 += __shfl_xor(v4, 16); v4 += __shfl_xor(v4, 32);
    if(quad == 0){
      int ch = t*16 + l15;
      atomicAdd(&cs[0][ch], v0); atomicAdd(&cs[1][ch], v1);
      atomicAdd(&cs[2][ch], v2); atomicAdd(&cs[3][ch], v3);
      atomicAdd(&cs[4][ch], v4);
    }
  }
  __syncthreads();
  float* slab = CS + (size_t)blockIdx.x*320;
  const float* c1 = &cs[0][0];
  slab[tid] = c1[tid];
  if(tid < 64) slab[256 + tid] = c1[256 + tid];
}

// ------- StatB: GN2 params + analytic GN3 stats -> fused affine coeffs ------
__global__ __launch_bounds__(256) void k_statB(const float* __restrict__ CS,
                                               const float* __restrict__ PB,
                                               float* __restrict__ CF){
  __shared__ float chs[5][64];
  __shared__ float mu2s[4], rs2s[4], tg[4], tq[4], mu3s[4], rs3s[4];
  int br = blockIdx.x >> 2, b = blockIdx.x & 3;
  int tid = threadIdx.x;
  const float* base = CS + ((size_t)(br*256 + b*64))*320;
  float* c1 = &chs[0][0];
  for(int v = tid; v < 320; v += 256){
    float s = 0.f;
    for(int k = 0; k < 64; k++) s += base[(size_t)k*320 + v];
    c1[v] = s;
  }
  __syncthreads();
  if(tid < 4){
    float s = 0.f, q = 0.f;
    for(int o = tid*16; o < tid*16 + 16; o++){ s += chs[0][o]; q += chs[1][o]; }
    float mean = s/262144.f, var = q/262144.f - mean*mean;
    mu2s[tid] = mean; rs2s[tid] = rsqrtf(fmaxf(var, 0.f) + EPSV);
    tg[tid] = 0.f; tq[tid] = 0.f;
  }
  __syncthreads();
  const float* pb = PB + br*2048;
  if(tid < 64){
    int o = tid, g = o >> 4;
    float w2v = pb[832 + o], b2v = pb[896 + o];
    float gw = w2v*rs2s[g], gb = b2v - mu2s[g]*rs2s[g]*w2v;
    float Sh = chs[0][o], Sh2 = chs[1][o], Sz = chs[2][o], Sz2 = chs[3][o], Shz = chs[4][o];
    float st = gw*Sh + Sz + 16384.f*gb;
    float sq = gw*gw*Sh2 + Sz2 + 16384.f*gb*gb + 2.f*gw*Shz + 2.f*gw*gb*Sh + 2.f*gb*Sz;
    atomicAdd(&tg[g], st); atomicAdd(&tq[g], sq);
  }
  __syncthreads();
  if(tid < 4){
    float mean = tg[tid]/262144.f, var = tq[tid]/262144.f - mean*mean;
    mu3s[tid] = mean; rs3s[tid] = rsqrtf(fmaxf(var, 0.f) + EPSV);
  }
  __syncthreads();
  if(tid < 64){
    int o = tid, g = o >> 4;
    float w2v = pb[832 + o], b2v = pb[896 + o];
    float gw = w2v*rs2s[g], gb = b2v - mu2s[g]*rs2s[g]*w2v;
    float w3v = pb[960 + o], b3v = pb[1024 + o];
    float gw3 = w3v*rs3s[g], gb3 = b3v - mu3s[g]*rs3s[g]*w3v;
    float* cf = CF + (size_t)(br*4 + b)*192;
    cf[o]       = gw*gw3;          // alpha (h2 coefficient)
    cf[64 + o]  = gw3;             // beta  (z coefficient)
    cf[128 + o] = gb*gw3 + gb3;    // gamma
  }
}

// ------- Final: out = alpha*h2 + beta*z + gamma, float4, in place -----------
__global__ __launch_bounds__(256) void k_final(const float* __restrict__ z,
                                               const float* __restrict__ CF,
                                               float* __restrict__ out){
  int tid = blockIdx.x*256 + threadIdx.x;
  const float4* z4 = (const float4*)z;
  const float4* cf4 = (const float4*)CF;
  float4* o4 = (float4*)out;
  #pragma unroll
  for(int r = 0; r < 8; r++){
    int i4 = r*262144 + tid;
    int s = i4 >> 18;                 // (b*2+br)
    int b = s >> 1, br = s & 1;
    int cbase = (br*4 + b)*48 + (i4 & 15);
    float4 a = cf4[cbase], bb = cf4[cbase + 16], g = cf4[cbase + 32];
    float4 h = o4[i4], zv = z4[i4];
    o4[i4] = make_float4(h.x*a.x + zv.x*bb.x + g.x,
                         h.y*a.y + zv.y*bb.y + g.y,
                         h.z*a.z + zv.z*bb.z + g.z,
                         h.w*a.w + zv.w*bb.w + g.w);
  }
}

extern "C" void kernel_launch(void* const* d_in, const int* in_sizes, int n_in,
                              void* d_out, int out_size, void* d_ws, size_t ws_size,
                              hipStream_t stream){
  const float* z   = (const float*)d_in[0];
  const float* x   = (const float*)d_in[1];
  const float* fw1 = (const float*)d_in[2];
  const float* fw2 = (const float*)d_in[3];
  char* ws = (char*)d_ws;
  // workspace layout (byte offsets)
  float2* Y   = (float2*)(ws + 0);           // 4,194,304 B
  float2* X2  = (float2*)(ws + 4194304);     // 1,048,576 B
  float2* T   = Y;                           // alias: Y dead after k_xdft
  bf16*   XO  = (bf16*)(ws + 5242880);       // 8,388,608 B
  float*  ST  = (float*)(ws + 13631488);     // 2,048 B
  short*  W1g = (short*)(ws + 13633536);     // 65,536 B
  short*  W2g = (short*)(ws + 13699072);     // 65,536 B
  float2* TWY = (float2*)(ws + 13764608);    // 16,384 B
  float2* TWX = (float2*)(ws + 13780992);    // 32,768 B
  float*  PB  = (float*)(ws + 13813760);     // 16,384 B
  float2* FWT = (float2*)(ws + 13830144);    // 16,777,216 B -> ends 30,607,360
  // Aliases into the FWT region (FWT dead after k_mix):
  float*  Cg  = (float*)(ws + 13830144);     // 65,536 B  (4 x 64 x 64), zeroed in k_inv2
  float*  SX  = Cg + 16384;                  // 1,024 B   (4 x 64), zeroed in k_inv2
  float*  CS  = (float*)(ws + 14878720);     // 655,360 B (512 slabs x 320)
  float*  CF  = (float*)(ws + 15927296);     // 6,144 B   (8 x 192)

  const float* p[20];
  for(int i = 0; i < 20; i++) p[i] = (const float*)d_in[4 + i];

  k_prep_ydft<<<1314, 256, 0, stream>>>(x, z, fw1, fw2, FWT,
                                  p[0],p[1],p[2],p[3],p[4],p[5],p[6],p[7],p[8],p[9],
                                  p[10],p[11],p[12],p[13],p[14],p[15],p[16],p[17],p[18],p[19],
                                  W1g, W2g, TWY, TWX, PB, ST, Y);
  k_xdft<<<256, 512, 0, stream>>>(Y, TWX, X2);
  k_mix<<<256, 512, 0, stream>>>(X2, FWT);
  k_inv1<<<256, 512, 0, stream>>>(X2, TWX, T);
  k_inv2<<<512, 256, 0, stream>>>(T, TWY, XO, Cg);
  k_cov<<<128, 256, 0, stream>>>(XO, Cg, SX);
  k_stat<<<128, 256, 0, stream>>>(Cg, SX, W1g, PB, ST);
  k_ffmain<<<512, 256, 0, stream>>>(XO, W1g, W2g, PB, ST, z, CS, (float*)d_out);
  k_statB<<<8, 256, 0, stream>>>(CS, PB, CF);
  k_final<<<1024, 256, 0, stream>>>(z, CF, (float*)d_out);
}